// Round 4
// baseline (746.901 us; speedup 1.0000x reference)
//
#include <hip/hip_runtime.h>

typedef unsigned short u16;
typedef unsigned int   u32;
typedef unsigned long long u64;
typedef __bf16 bf16x8 __attribute__((ext_vector_type(8)));
typedef float  floatx4 __attribute__((ext_vector_type(4)));

#define DEV static __device__ __forceinline__

DEV u16 f2bf(float f){ u32 x = __float_as_uint(f); return (u16)((x + 0x7fffu + ((x>>16)&1u)) >> 16); }
DEV float bf2f(u16 h){ return __uint_as_float(((u32)h)<<16); }
// pack two f32 -> two bf16 (RNE), one instruction. dst.lo=cvt(a), dst.hi=cvt(b)
DEV u32 cvt_pk_bf16(float a, float b){ u32 r; asm("v_cvt_pk_bf16_f32 %0, %1, %2" : "=v"(r) : "v"(a), "v"(b)); return r; }

DEV void load_lds16(const u16* g, u16* l){
  __builtin_amdgcn_global_load_lds((const __attribute__((address_space(1))) u32*)g,
                                   (__attribute__((address_space(3))) u32*)l, 16, 0, 0);
}

// ---------------------------------------------------------------------------
// LDS swizzle for [rows][32 u16] tiles. NOTE (round-2 post-mortem): measured
// bank-conflict counter is unchanged by this (4 cyc/ds_read_b128 is inherent
// b128 serialization, m134), so it is NOT a perf lever — kept because it is
// measured-neutral and already verified.
// ---------------------------------------------------------------------------
DEV u32 unswz64(u32 p){
  u32 r0 = ((p>>6) ^ (p>>8)) & 1u;
  u32 b4 = ((p>>4) & 1u) ^ r0;
  u32 b5 = ((p>>5) ^ (p>>7)) & 1u;
  return (p & ~0x70u) | (b4<<4) | (b5<<5) | (r0<<6);
}
DEV bf16x8 ldfrag(const u16* base, int row, int lane){
  u32 off = ((u32)row<<6) + (((u32)lane>>4)<<4);
  off ^= (u32)(row&7)<<4;
  return *(const bf16x8*)((const char*)base + off);
}

// ---------------------------------------------------------------------------
// Generic NT GEMM: C[m,n] = sum_k A[m,k]*B[n,k]  (A,B bf16 row-major, C fp32)
// BM in {64,128}, BN in {64,128}, BK=32, 256 threads (4 waves as 2x2).
// MODE 0: C fp32 (+optional bias[n]), stores guarded by col<ncmax.
// ---------------------------------------------------------------------------
template<int BM, int BN, int MODE>
__global__ __launch_bounds__(256) void gemm_bt(
    const u16* __restrict__ A, const u16* __restrict__ Bm, float* __restrict__ C,
    const float* __restrict__ bias, int K, int lda, int ldb, int ldc, int ncmax,
    long long sA, long long sB, long long sC,
    u16* __restrict__ vout, float* __restrict__ resb, const float* __restrict__ araw,
    int order, int accum)
{
  constexpr int BK = 32;
  constexpr int MT = BM/32;               // m-tiles per wave (wave covers BM/2 rows)
  constexpr int NT = (BN/2)/16;           // n-tiles per wave
  __shared__ u16 smem[8704];              // staging (<=8192 u16) / 64x136 transpose
  u16* As = smem;                         // BM*BK u16
  u16* Bs = smem + BM*BK;                 // BN*BK u16

  const int tid = threadIdx.x, wid = tid>>6, lane = tid&63;
  const int z = blockIdx.z;
  const int m0 = blockIdx.y * BM, n0 = blockIdx.x * BN;
  const u16* Ab = A + (long long)z*sA;
  const u16* Bb = Bm + (long long)z*sB;

  // inverse-swizzled staging source coordinates (linear LDS dest)
  const u32 g = unswz64((u32)tid*16);
  const int srow = g>>6, schunk = (g&63)>>1;
  const u16* ga0 = Ab + (long long)(m0 + srow)*lda + schunk;
  const u16* gb0 = Bb + (long long)(n0 + srow)*ldb + schunk;
  const u16* ga1 = (BM==128) ? Ab + (long long)(m0 + 64 + srow)*lda + schunk : nullptr;
  const u16* gb1 = (BN==128) ? Bb + (long long)(n0 + 64 + srow)*ldb + schunk : nullptr;

  u16* lA0 = As + (wid*16)*BK;
  u16* lA1 = As + (64 + wid*16)*BK;
  u16* lB0 = Bs + (wid*16)*BK;
  u16* lB1 = Bs + (64 + wid*16)*BK;

  const int wm = wid>>1, wn = wid&1;
  const int lr = lane&15, lq = lane>>4;

  floatx4 acc[MT][NT] = {};

  for (int k = 0; k < K; k += BK) {
    __syncthreads();
    load_lds16(ga0 + k, lA0);
    if constexpr (BM == 128) load_lds16(ga1 + k, lA1);
    load_lds16(gb0 + k, lB0);
    if constexpr (BN == 128) load_lds16(gb1 + k, lB1);
    __syncthreads();
    bf16x8 af[MT];
#pragma unroll
    for (int mt=0; mt<MT; ++mt)
      af[mt] = ldfrag(As, wm*(BM/2) + mt*16 + lr, lane);
#pragma unroll
    for (int nt=0; nt<NT; ++nt) {
      bf16x8 bfr = ldfrag(Bs, wn*(BN/2) + nt*16 + lr, lane);
#pragma unroll
      for (int mt=0; mt<MT; ++mt)
        acc[mt][nt] = __builtin_amdgcn_mfma_f32_16x16x32_bf16(af[mt], bfr, acc[mt][nt], 0, 0, 0);
    }
  }

  if constexpr (MODE == 0) {
    float* Cb = C + (long long)z*sC;
#pragma unroll
    for (int nt=0; nt<NT; ++nt) {
      const int col = n0 + wn*(BN/2) + nt*16 + lr;
      if (col < ncmax) {
        const float bv = bias ? bias[col] : 0.f;
#pragma unroll
        for (int mt=0; mt<MT; ++mt) {
#pragma unroll
          for (int r=0; r<4; ++r) {
            const int row = m0 + wm*(BM/2) + mt*16 + lq*4 + r;
            Cb[(long long)row*ldc + col] = acc[mt][nt][r] + bv;
          }
        }
      }
    }
  } else {
    const int h = z & 15;
    const float alpha = 1.f/(1.f + __expf(-araw[order*16 + h]));
    float* rb = resb + (long long)z * 65536;   // res[z][1024][64]
    __syncthreads();                           // staging LDS reuse as transpose buf
#pragma unroll
    for (int nt=0; nt<NT; ++nt) {
      const int d = wn*32 + nt*16 + lr;
#pragma unroll
      for (int mt=0; mt<MT; ++mt) {
#pragma unroll
        for (int r=0; r<4; ++r) {
          const int row = wm*(BM/2) + mt*16 + lq*4 + r;
          const float v = acc[mt][nt][r];
          const long long ri = (long long)(m0+row)*64 + d;
          rb[ri] = accum ? (rb[ri] + alpha*v) : (alpha*v);
          smem[d*136 + row] = f2bf(v);
        }
      }
    }
    __syncthreads();
    const int dd = tid>>2, cc = (tid&3)*(BM/4);
    u16* vp = vout + (long long)z*75776 + (long long)dd*1184 + m0 + cc;  // vout[z][64][1184]
    const u16* sp = smem + dd*136 + cc;
#pragma unroll
    for (int j=0; j<BM/4; j+=8) {
      uint4 uu;
      uu.x = sp[j+0] | ((u32)sp[j+1]<<16);
      uu.y = sp[j+2] | ((u32)sp[j+3]<<16);
      uu.z = sp[j+4] | ((u32)sp[j+5]<<16);
      uu.w = sp[j+6] | ((u32)sp[j+7]<<16);
      *(uint4*)(vp + j) = uu;
    }
  }
}

// ---------------------------------------------------------------------------
// AV kernel v3: out[i,d] = sum_j P[i,j] * V^T[d,j], per z.
// Round-3 post-mortem: v2's depth-3 reg pipeline = 6 outstanding 16B
// loads/wave; with P streaming from HBM (~900 cy) that is ~2 TB/s effective
// (latency x in-flight-bytes bound), ~35 us/dispatch vs ~15 us HBM floor.
// v3: asymmetric depths matched to latency — A (P, HBM stream) depth 6,
// B (V, L2-resident via XCD clustering) depth 3. 9 x bf16x8 = 36 VGPR of
// buffers, ~58 total -> still 8 blocks/CU (launch_bounds(256,8)).
// K is a template param so the k-loop FULLY unrolls: all buffer indices are
// compile-time (rule #20 — no scratch), and the a[]/b[] WAR deps structurally
// cap compiler hoisting at the intended pipeline depth.
// K ascending, single MFMA chain -> numerics identical to v1/v2.
// ---------------------------------------------------------------------------
template<int K>
__global__ __launch_bounds__(256, 8) void av16(
    const u16* __restrict__ P,    // [z][1024][1184]
    const u16* __restrict__ V,    // [z][64][1184]
    u16* __restrict__ vout,       // [z][64][1184]
    float* __restrict__ resb,     // [z][1024][64]
    const float* __restrict__ araw, int order, int accum, int wv)
{
  const int tid = threadIdx.x, wid = tid>>6, lane = tid&63;
  const int L = blockIdx.x;
  const int z = (L & 7) + ((L >> 9) << 3);  // 4 z per XCD, all m-tiles clustered
  const int m0 = ((L >> 3) & 63) * 16;
  const int lr = lane&15, lq = lane>>4;

  // A frag: lane(lr,lq) -> P[m0+lr][k + lq*8..+7]; B frag: V[wid*16+lr][k + lq*8..+7]
  const u16* pA = P + (long long)z*1212416 + (long long)(m0 + lr)*1184 + lq*8;
  const u16* pB = V + (long long)z*75776  + (long long)(wid*16 + lr)*1184 + lq*8;

  constexpr int nk = K >> 5;     // 37 or 32
  constexpr int DA = 6, DB = 3;

  bf16x8 a[DA], b[DB];
#pragma unroll
  for (int p=0;p<DA;++p) a[p] = *(const bf16x8*)(pA + p*32);
#pragma unroll
  for (int p=0;p<DB;++p) b[p] = *(const bf16x8*)(pB + p*32);

  floatx4 acc = {0.f,0.f,0.f,0.f};
#pragma unroll
  for (int s=0;s<nk;++s){
    acc = __builtin_amdgcn_mfma_f32_16x16x32_bf16(a[s%DA], b[s%DB], acc, 0, 0, 0);
    if (s + DA < nk) a[s%DA] = *(const bf16x8*)(pA + (s+DA)*32);
    if (s + DB < nk) b[s%DB] = *(const bf16x8*)(pB + (s+DB)*32);
  }

  const int h = z & 15;
  const float alpha = 1.f/(1.f + __expf(-araw[order*16 + h]));
  const int d = wid*16 + lr;       // C col = lane&15 -> B row = d
  float* rb = resb + (long long)z * 65536;
#pragma unroll
  for (int r=0; r<4; ++r){
    const float v = acc[r];        // C row = lq*4 + r
    const long long ri = (long long)(m0 + lq*4 + r)*64 + d;
    rb[ri] = accum ? (rb[ri] + alpha*v) : (alpha*v);
  }
  if (wv){
    u32 w0 = f2bf(acc[0]) | ((u32)f2bf(acc[1])<<16);
    u32 w1 = f2bf(acc[2]) | ((u32)f2bf(acc[3])<<16);
    u16* vp = vout + (long long)z*75776 + (long long)d*1184 + m0 + lq*4;
    *(uint2*)vp = uint2{w0, w1};
  }
}

// ---------------------------------------------------------------------------
// Fused scores + top-k + softmax, v4 (unchanged).
// ---------------------------------------------------------------------------
__global__ __launch_bounds__(1024, 8) void score_topk(
    const u16* __restrict__ qF,   // [z][64][6][64][8]
    const u16* __restrict__ kxF,  // [z][80][6][64][8]
    u16* __restrict__ P)          // [z][1024][1184]
{
  constexpr int SROW = 1156;
  __shared__ float sm[16*SROW];   // 73,984 B -> 2 blocks/CU
  const int tid = threadIdx.x, wid = tid>>6, lane = tid&63;
  const int L = blockIdx.x;
  const int z  = (L & 7) + ((L >> 9) << 3);
  const int mt = (L >> 3) & 63;
  const int m0 = mt*16;
  const int lr = lane&15, lq = lane>>4;

  const u16* Aq = qF + (((long long)z*64 + mt)*6*64 + lane)*8;
  const u16* Bq = kxF + ((long long)z*80*6*64 + lane)*8;

  bf16x8 af[6];
#pragma unroll
  for (int kc=0;kc<6;++kc) af[kc] = *(const bf16x8*)(Aq + kc*512);

  const int base = wid*5;
  {
    floatx4 acc[5];
#pragma unroll
    for (int t=0;t<5;++t) acc[t] = floatx4{0.f,0.f,0.f,0.f};
#pragma unroll
    for (int t=0;t<5;++t){
      if (base + t < 73){
        const u16* bp = Bq + (long long)(base+t)*3072;   // 6*512
        bf16x8 b0 = *(const bf16x8*)(bp);
        bf16x8 b1 = *(const bf16x8*)(bp + 512);
        bf16x8 b2 = *(const bf16x8*)(bp + 1024);
        bf16x8 b3 = *(const bf16x8*)(bp + 1536);
        bf16x8 b4 = *(const bf16x8*)(bp + 2048);
        bf16x8 b5 = *(const bf16x8*)(bp + 2560);
        acc[t] = __builtin_amdgcn_mfma_f32_16x16x32_bf16(af[0], b0, acc[t], 0, 0, 0);
        acc[t] = __builtin_amdgcn_mfma_f32_16x16x32_bf16(af[1], b1, acc[t], 0, 0, 0);
        acc[t] = __builtin_amdgcn_mfma_f32_16x16x32_bf16(af[2], b2, acc[t], 0, 0, 0);
        acc[t] = __builtin_amdgcn_mfma_f32_16x16x32_bf16(af[3], b3, acc[t], 0, 0, 0);
        acc[t] = __builtin_amdgcn_mfma_f32_16x16x32_bf16(af[4], b4, acc[t], 0, 0, 0);
        acc[t] = __builtin_amdgcn_mfma_f32_16x16x32_bf16(af[5], b5, acc[t], 0, 0, 0);
      }
    }
#pragma unroll
    for (int t=0;t<5;++t){
      if (base + t < 73){
        const int col = (base+t)*16 + lr;
        if (col < 1153){
#pragma unroll
          for (int r=0;r<4;++r) sm[(lq*4+r)*SROW + col] = acc[t][r];
        }
      }
    }
  }
  __syncthreads();

  {
    const int row = wid;
    const int i = m0 + row;
    float* R = sm + row*SROW;

    float v[16];
#pragma unroll
    for (int x=0;x<8;++x){
      float2 f = *(const float2*)(R + x*128 + lane*2);
      v[2*x] = f.x; v[2*x+1] = f.y;
    }
#pragma unroll
    for (int x=0;x<16;++x){
      const int j = (x>>1)*128 + lane*2 + (x&1);
      int dl = i - j; dl = dl > 64 ? 64 : (dl < -64 ? -64 : dl);
      v[x] += R[1024 + dl + 64];
    }
    u32 u[16];
#pragma unroll
    for (int x=0;x<16;++x){
      u32 bb = __float_as_uint(v[x]);
      u[x] = bb ^ ((u32)((int)bb >> 31) | 0x80000000u);
    }
    u32 thr = 0;
#pragma unroll 1
    for (int bit=31; bit>=0; --bit){
      const u32 cand = thr | (1u<<bit);
      int c = 0;
#pragma unroll
      for (int x=0;x<16;++x) c += __popcll(__ballot(u[x] >= cand));
      if (c == 256){
        u32 mn = 0xFFFFFFFFu;
#pragma unroll
        for (int x=0;x<16;++x) if (u[x] >= cand && u[x] < mn) mn = u[x];
        for (int o=32;o;o>>=1){ u32 t = __shfl_xor(mn, o); mn = t < mn ? t : mn; }
        thr = mn;
        break;
      }
      if (c > 256) thr = cand;
    }
    float m = -3.0e38f;
#pragma unroll
    for (int x=0;x<16;++x) m = fmaxf(m, v[x]);
    for (int o=32;o;o>>=1) m = fmaxf(m, __shfl_xor(m, o));
    float e[16]; float Z = 0.f;
#pragma unroll
    for (int x=0;x<16;++x){
      e[x] = (u[x] >= thr) ? __expf(v[x]-m) : 0.f;
      Z += e[x];
    }
    for (int o=32;o;o>>=1) Z += __shfl_xor(Z, o);
    const float rz = 1.f / Z;

    u16* Pr = P + ((long long)z*1024 + i)*1184;
    u32* Pr32 = (u32*)Pr;
    float s0 = 0.f, s1 = 0.f;
#pragma unroll
    for (int x=0;x<8;++x){
      const float p0 = e[2*x]*rz, p1 = e[2*x+1]*rz;
      *(float2*)(R + x*128 + lane*2) = float2{p0, p1};
      Pr32[x*64 + lane] = cvt_pk_bf16(p0, p1);
      const int j0 = x*128 + lane*2;
      if (j0     >= i+64) s0 += p0;     // dist bucket t=0
      if (j0     <= i-64) s1 += p0;     // dist bucket t=128
      if (j0 + 1 >= i+64) s0 += p1;
      if (j0 + 1 <= i-64) s1 += p1;
    }
    for (int o=32;o;o>>=1){ s0 += __shfl_xor(s0,o); s1 += __shfl_xor(s1,o); }
    {
      const int t = lane + 1;        // 1..64
      const int j = i + 64 - t;
      const float wv = (j>=0 && j<1024) ? R[j] : 0.f;
      Pr[1024 + t] = f2bf(wv);
      if (lane < 63){
        const int t2 = lane + 65;    // 65..127
        const int j2 = i + 64 - t2;
        const float wv2 = (j2>=0 && j2<1024) ? R[j2] : 0.f;
        Pr[1024 + t2] = f2bf(wv2);
      }
      if (lane == 0){ Pr[1024] = f2bf(s0); Pr[1152] = f2bf(s1); }
      if (lane >= 33) Pr[1120 + lane] = 0;  // zero cols 1153..1183
    }
  }
}

// ---------------------------------------------------------------------------
// Elementwise prep kernels
// ---------------------------------------------------------------------------
__global__ __launch_bounds__(256) void planeize(const float* __restrict__ src, u16* __restrict__ dst,
                                                int total, int modeB){
  int idx = blockIdx.x*256 + threadIdx.x;
  if (idx >= total) return;
  int c = idx & 1023, r = idx >> 10;
  float v = src[idx];
  u16 hi = f2bf(v); u16 lo = f2bf(v - bf2f(hi));
  u16* d = dst + (long long)r*3072 + c;
  if (modeB){ d[0]=hi; d[1024]=hi; d[2048]=lo; }
  else      { d[0]=hi; d[1024]=lo; d[2048]=hi; }
}

// qkv -> qF (A planes hi|lo|hi) and kxF rows 0..1023 (B planes hi|hi|lo, k*0.125),
// both in MFMA-fragment-swizzled layout.
__global__ __launch_bounds__(256) void build_qk(const float* __restrict__ qkv,
                                                u16* __restrict__ qF, u16* __restrict__ kxF){
  int idx = blockIdx.x*256 + threadIdx.x;   // ((b*16+h)*1024+n)*64+d
  int d = idx & 63, n = (idx>>6) & 1023, bh = idx >> 16;
  int b = bh >> 4, h = bh & 15;
  long long src = (long long)(b*1024 + n)*3072 + h*64 + d;
  float qv = qkv[src];
  float kv = qkv[src + 1024] * 0.125f;
  u16 qhi=f2bf(qv), qlo=f2bf(qv - bf2f(qhi));
  u16 khi=f2bf(kv), klo=f2bf(kv - bf2f(khi));
  const int lane = (n&15) + (((d&31)>>3)<<4);
  const int elem = d&7, kc0 = d>>5;
  u16* q = qF + ((((long long)bh*64 + (n>>4))*6*64) + lane)*8 + elem;
  q[(kc0+0)*512] = qhi; q[(kc0+2)*512] = qlo; q[(kc0+4)*512] = qhi;
  u16* kx = kxF + ((((long long)bh*80 + (n>>4))*6*64) + lane)*8 + elem;
  kx[(kc0+0)*512] = khi; kx[(kc0+2)*512] = khi; kx[(kc0+4)*512] = klo;
}

// kxF rows 1024..1279: rel_k_emb planes (B-mode), zero pad rows; swizzled.
__global__ __launch_bounds__(256) void build_kxrel(const float* __restrict__ relk, u16* __restrict__ kxF){
  int idx = blockIdx.x*256 + threadIdx.x;   // (bh, t:256, d:64)
  int d = idx & 63, t = (idx>>6) & 255, bh = idx >> 14;
  u16 hi=0, lo=0;
  if (t < 129){ float v = relk[t*64 + d]; hi = f2bf(v); lo = f2bf(v - bf2f(hi)); }
  const int nrow = 1024 + t;
  const int lane = (t&15) + (((d&31)>>3)<<4);
  const int elem = d&7, kc0 = d>>5;
  u16* kx = kxF + ((((long long)bh*80 + (nrow>>4))*6*64) + lane)*8 + elem;
  kx[(kc0+0)*512] = hi; kx[(kc0+2)*512] = hi; kx[(kc0+4)*512] = lo;
}

__global__ __launch_bounds__(256) void build_vT(const float* __restrict__ qkv, u16* __restrict__ vA){
  __shared__ float tb[64][65];
  int bh = blockIdx.x >> 4, ntile = blockIdx.x & 15;
  int b = bh >> 4, h = bh & 15;
  int tid = threadIdx.x;
  int nl = tid >> 2, dc = (tid & 3)*16;
  const float* sp = qkv + (long long)(b*1024 + ntile*64 + nl)*3072 + 2048 + h*64 + dc;
#pragma unroll
  for (int j=0;j<16;j+=4){
    float4 f = *(const float4*)(sp + j);
    tb[dc+j+0][nl]=f.x; tb[dc+j+1][nl]=f.y; tb[dc+j+2][nl]=f.z; tb[dc+j+3][nl]=f.w;
  }
  __syncthreads();
  int d = tid >> 2, nc = (tid & 3)*16;
  u16* dp = vA + ((long long)bh*64 + d)*1184 + ntile*64 + nc;
#pragma unroll
  for (int j=0;j<16;j+=8){
    u16 a0=f2bf(tb[d][nc+j+0]), a1=f2bf(tb[d][nc+j+1]), a2=f2bf(tb[d][nc+j+2]), a3=f2bf(tb[d][nc+j+3]);
    u16 a4=f2bf(tb[d][nc+j+4]), a5=f2bf(tb[d][nc+j+5]), a6=f2bf(tb[d][nc+j+6]), a7=f2bf(tb[d][nc+j+7]);
    uint4 uu; uu.x=a0|((u32)a1<<16); uu.y=a2|((u32)a3<<16); uu.z=a4|((u32)a5<<16); uu.w=a6|((u32)a7<<16);
    *(uint4*)(dp + j) = uu;
  }
}

__global__ __launch_bounds__(256) void build_vText(const float* __restrict__ relv, u16* __restrict__ vA){
  int idx = blockIdx.x*256 + threadIdx.x;   // (bh, d, t:160)
  int t = idx % 160; int rest = idx / 160; int d = rest & 63; int bh = rest >> 6;
  u16 hv = 0;
  if (t < 129) hv = f2bf(relv[t*64 + d]);
  vA[((long long)bh*64 + d)*1184 + 1024 + t] = hv;
}

__global__ __launch_bounds__(256) void build_resS(const float* __restrict__ res, u16* __restrict__ resS){
  int idx = blockIdx.x*256 + threadIdx.x;
  int d = idx & 63, n = (idx>>6) & 1023, bh = idx >> 16;
  int b = bh >> 4, h = bh & 15;
  float v = res[idx];
  u16 hi = f2bf(v), lo = f2bf(v - bf2f(hi));
  u16* p = resS + (long long)(b*1024 + n)*3072 + h*64 + d;
  p[0]=hi; p[1024]=lo; p[2048]=hi;
}

// ---------------------------------------------------------------------------
extern "C" void kernel_launch(void* const* d_in, const int* in_sizes, int n_in,
                              void* d_out, int out_size, void* d_ws, size_t ws_size,
                              hipStream_t stream) {
  const float* x    = (const float*)d_in[0];
  const float* Wqkv = (const float*)d_in[1];
  const float* bqkv = (const float*)d_in[2];
  const float* Wout = (const float*)d_in[3];
  const float* bout = (const float*)d_in[4];
  const float* relk = (const float*)d_in[5];
  const float* relv = (const float*)d_in[6];
  const float* araw = (const float*)d_in[7];
  float* out = (float*)d_out;

  char* w = (char*)d_ws;
  size_t off = 0;
  auto take = [&](size_t bytes)->char*{ char* p = w + off; off += (bytes + 255) & ~(size_t)255; return p; };

  // regionA (90 MB): phase1 {xS|wqS|qkv32} -> per-half P (77.6 MB) -> {resS|woS}
  char* regionA = take(94371840);
  u16*   xS    = (u16*)  (regionA);
  u16*   wqS   = (u16*)  (regionA + 25165824);
  float* qkv32 = (float*)(regionA + 44040192);
  u16*   Ph    = (u16*)  (regionA);         // [32][1024][1184] u16 per half
  u16*   resS  = (u16*)  (regionA);
  u16*   woS   = (u16*)  (regionA + 25165824);
  u16*   qF    = (u16*)take(25165824);      // [64][64][6][64][8]
  u16*   kxF   = (u16*)take(31457280);      // [64][80][6][64][8]
  u16*   vA    = (u16*)take(9699328);       // [64][64][1184]
  u16*   vB    = (u16*)take(9699328);
  float* res   = (float*)take(16777216);    // [64][1024][64]
  (void)ws_size; (void)in_sizes; (void)n_in; (void)out_size;
  // total ~187 MiB

  // phase 1: QKV projection. qk at split-fp32 (K=3072 planes); v hi*hi (K=1024).
  planeize<<<16384,256,0,stream>>>(x,    xS,  4194304, 0);
  planeize<<<12288,256,0,stream>>>(Wqkv, wqS, 3145728, 1);
  gemm_bt<128,128,0><<<dim3(16,32,1),256,0,stream>>>(xS, wqS, qkv32, bqkv,
      3072, 3072, 3072, 3072, 2048, 0, 0, 0, nullptr, nullptr, nullptr, 0, 0);
  gemm_bt<128,128,0><<<dim3(8,32,1),256,0,stream>>>(xS, wqS + (long long)2048*3072,
      qkv32 + 2048, bqkv + 2048,
      1024, 3072, 3072, 3072, 1024, 0, 0, 0, nullptr, nullptr, nullptr, 0, 0);
  build_qk   <<<16384,256,0,stream>>>(qkv32, qF, kxF);
  build_kxrel<<<4096, 256,0,stream>>>(relk, kxF);
  build_vT   <<<1024, 256,0,stream>>>(qkv32, vA);
  build_vText<<<2560, 256,0,stream>>>(relv, vA);

  // phases 2+3 per 32-head half: fused scores/topk/softmax -> P, then 3x AV
  for (int half = 0; half < 2; ++half) {
    const long long zo = (long long)half * 32;
    score_topk<<<2048,1024,0,stream>>>(qF + zo*196608, kxF + zo*245760, Ph);
    av16<1184><<<2048,256,0,stream>>>(Ph, vA + zo*75776, vB + zo*75776, res + zo*65536,
        araw, 0, 0, 1);
    av16<1024><<<2048,256,0,stream>>>(Ph, vB + zo*75776, vA + zo*75776, res + zo*65536,
        araw, 1, 1, 1);
    av16<1024><<<2048,256,0,stream>>>(Ph, vA + zo*75776, vB + zo*75776, res + zo*65536,
        araw, 2, 1, 0);
  }

  // output projection (fp32 via split planes), BM=64 for 512-block occupancy
  build_resS<<<16384,256,0,stream>>>(res, resS);
  planeize  <<<4096, 256,0,stream>>>(Wout, woS, 1048576, 1);
  gemm_bt<64,128,0><<<dim3(8,64,1),256,0,stream>>>(resS, woS, out, bout,
      3072, 3072, 3072, 1024, 1024, 0, 0, 0, nullptr, nullptr, nullptr, 0, 0);
}

// Round 5
// 596.442 us; speedup vs baseline: 1.2523x; 1.2523x over previous
//
#include <hip/hip_runtime.h>

typedef unsigned short u16;
typedef unsigned int   u32;
typedef unsigned long long u64;
typedef __bf16 bf16x8 __attribute__((ext_vector_type(8)));
typedef float  floatx4 __attribute__((ext_vector_type(4)));

#define DEV static __device__ __forceinline__

DEV u16 f2bf(float f){ u32 x = __float_as_uint(f); return (u16)((x + 0x7fffu + ((x>>16)&1u)) >> 16); }
DEV float bf2f(u16 h){ return __uint_as_float(((u32)h)<<16); }
// pack two f32 -> two bf16 (RNE), one instruction. dst.lo=cvt(a), dst.hi=cvt(b)
DEV u32 cvt_pk_bf16(float a, float b){ u32 r; asm("v_cvt_pk_bf16_f32 %0, %1, %2" : "=v"(r) : "v"(a), "v"(b)); return r; }

DEV void load_lds16(const u16* g, u16* l){
  __builtin_amdgcn_global_load_lds((const __attribute__((address_space(1))) u32*)g,
                                   (__attribute__((address_space(3))) u32*)l, 16, 0, 0);
}

// ---------------------------------------------------------------------------
// LDS swizzle for [rows][32 u16] tiles (verified bijective; measured-neutral
// on bank conflicts — kept because already validated in rounds 2-4).
// Read: byte ^= (row&7)<<4. Staging: LDS dest linear, global source byte =
// unswz64(linear dest byte) (row-count agnostic: bits 9+ pass through).
// ---------------------------------------------------------------------------
DEV u32 unswz64(u32 p){
  u32 r0 = ((p>>6) ^ (p>>8)) & 1u;
  u32 b4 = ((p>>4) & 1u) ^ r0;
  u32 b5 = ((p>>5) ^ (p>>7)) & 1u;
  return (p & ~0x70u) | (b4<<4) | (b5<<5) | (r0<<6);
}
DEV bf16x8 ldfrag(const u16* base, int row, int lane){
  u32 off = ((u32)row<<6) + (((u32)lane>>4)<<4);
  off ^= (u32)(row&7)<<4;
  return *(const bf16x8*)((const char*)base + off);
}

// ---------------------------------------------------------------------------
// gemm_bt: 256-thread 4-wave NT GEMM, kept ONLY for MODE 1 (AV epilogue) —
// the proven round-1 AV path (res (+)= alpha*C, vout = bf16(C)^T via LDS).
// ---------------------------------------------------------------------------
template<int BM, int BN, int MODE>
__global__ __launch_bounds__(256) void gemm_bt(
    const u16* __restrict__ A, const u16* __restrict__ Bm, float* __restrict__ C,
    const float* __restrict__ bias, int K, int lda, int ldb, int ldc, int ncmax,
    long long sA, long long sB, long long sC,
    u16* __restrict__ vout, float* __restrict__ resb, const float* __restrict__ araw,
    int order, int accum)
{
  constexpr int BK = 32;
  constexpr int MT = BM/32;               // m-tiles per wave (wave covers BM/2 rows)
  constexpr int NT = (BN/2)/16;           // n-tiles per wave
  __shared__ u16 smem[8704];              // staging (<=8192 u16) / 64x136 transpose
  u16* As = smem;                         // BM*BK u16
  u16* Bs = smem + BM*BK;                 // BN*BK u16

  const int tid = threadIdx.x, wid = tid>>6, lane = tid&63;
  const int z = blockIdx.z;
  const int m0 = blockIdx.y * BM, n0 = blockIdx.x * BN;
  const u16* Ab = A + (long long)z*sA;
  const u16* Bb = Bm + (long long)z*sB;

  // inverse-swizzled staging source coordinates (linear LDS dest)
  const u32 g = unswz64((u32)tid*16);
  const int srow = g>>6, schunk = (g&63)>>1;
  const u16* ga0 = Ab + (long long)(m0 + srow)*lda + schunk;
  const u16* gb0 = Bb + (long long)(n0 + srow)*ldb + schunk;

  u16* lA0 = As + (wid*16)*BK;
  u16* lB0 = Bs + (wid*16)*BK;

  const int wm = wid>>1, wn = wid&1;
  const int lr = lane&15, lq = lane>>4;

  floatx4 acc[MT][NT] = {};

  for (int k = 0; k < K; k += BK) {
    __syncthreads();
    load_lds16(ga0 + k, lA0);
    load_lds16(gb0 + k, lB0);
    __syncthreads();
    bf16x8 af[MT];
#pragma unroll
    for (int mt=0; mt<MT; ++mt)
      af[mt] = ldfrag(As, wm*(BM/2) + mt*16 + lr, lane);
#pragma unroll
    for (int nt=0; nt<NT; ++nt) {
      bf16x8 bfr = ldfrag(Bs, wn*(BN/2) + nt*16 + lr, lane);
#pragma unroll
      for (int mt=0; mt<MT; ++mt)
        acc[mt][nt] = __builtin_amdgcn_mfma_f32_16x16x32_bf16(af[mt], bfr, acc[mt][nt], 0, 0, 0);
    }
  }

  if constexpr (MODE == 0) {
    float* Cb = C + (long long)z*sC;
#pragma unroll
    for (int nt=0; nt<NT; ++nt) {
      const int col = n0 + wn*(BN/2) + nt*16 + lr;
      if (col < ncmax) {
        const float bv = bias ? bias[col] : 0.f;
#pragma unroll
        for (int mt=0; mt<MT; ++mt) {
#pragma unroll
          for (int r=0; r<4; ++r) {
            const int row = m0 + wm*(BM/2) + mt*16 + lq*4 + r;
            Cb[(long long)row*ldc + col] = acc[mt][nt][r] + bv;
          }
        }
      }
    }
  } else {
    const int h = z & 15;
    const float alpha = 1.f/(1.f + __expf(-araw[order*16 + h]));
    float* rb = resb + (long long)z * 65536;   // res[z][1024][64]
    __syncthreads();                           // staging LDS reuse as transpose buf
#pragma unroll
    for (int nt=0; nt<NT; ++nt) {
      const int d = wn*32 + nt*16 + lr;
#pragma unroll
      for (int mt=0; mt<MT; ++mt) {
#pragma unroll
        for (int r=0; r<4; ++r) {
          const int row = wm*(BM/2) + mt*16 + lq*4 + r;
          const float v = acc[mt][nt][r];
          const long long ri = (long long)(m0+row)*64 + d;
          rb[ri] = accum ? (rb[ri] + alpha*v) : (alpha*v);
          smem[d*136 + row] = f2bf(v);
        }
      }
    }
    __syncthreads();
    const int dd = tid>>2, cc = (tid&3)*(BM/4);
    u16* vp = vout + (long long)z*75776 + (long long)dd*1184 + m0 + cc;  // vout[z][64][1184]
    const u16* sp = smem + dd*136 + cc;
#pragma unroll
    for (int j=0; j<BM/4; j+=8) {
      uint4 uu;
      uu.x = sp[j+0] | ((u32)sp[j+1]<<16);
      uu.y = sp[j+2] | ((u32)sp[j+3]<<16);
      uu.z = sp[j+4] | ((u32)sp[j+5]<<16);
      uu.w = sp[j+6] | ((u32)sp[j+7]<<16);
      *(uint4*)(vp + j) = uu;
    }
  }
}

// ---------------------------------------------------------------------------
// gemm8: 512-thread 8-wave MODE-0 GEMM (round-4 post-mortem: the 4-wave
// version runs 2 waves/SIMD at grid 512 -> 20% occupancy; the 2-phase
// vmcnt(0)+barrier drain is unhidden). 8 waves as 2(m)x4(n), MT=BM/32,
// NT=2; ONE global_load_lds issue per operand per k-step (16B x 512thr
// covers the full 128x32 tile). Per-output MFMA chain identical to
// gemm_bt (K ascending, one mfma/k-step) -> bit-identical C.
// launch_bounds(512,4) caps VGPR at 128 (est. ~70, no spill);
// 2 blocks/CU x 8 waves = 4 waves/SIMD (2x the TLP).
// ---------------------------------------------------------------------------
template<int BM, int BN>
__global__ __launch_bounds__(512, 4) void gemm8(
    const u16* __restrict__ A, const u16* __restrict__ Bm, float* __restrict__ C,
    const float* __restrict__ bias, int K, int lda, int ldb, int ldc, int ncmax)
{
  constexpr int MT = (BM/2)/16;           // 4 (BM=128) or 2 (BM=64)
  constexpr int NT = (BN/4)/16;           // 2 (BN=128)
  __shared__ u16 As[BM*32];
  __shared__ u16 Bs[BN*32];

  const int tid = threadIdx.x, wid = tid>>6, lane = tid&63;
  const int m0 = blockIdx.y * BM, n0 = blockIdx.x * BN;

  const u32 g = unswz64((u32)tid*16);
  const int srow = g>>6, schunk = (g&63)>>1;
  const u16* ga0 = A  + (long long)(m0 + srow)*lda + schunk;  // used iff wid < BM/16
  const u16* gb0 = Bm + (long long)(n0 + srow)*ldb + schunk;

  u16* lA = As + (wid<<9);               // wave-uniform base: wave w -> rows 16w..16w+15
  u16* lB = Bs + (wid<<9);

  const int wm = wid>>2, wn = wid&3;
  const int lr = lane&15, lq = lane>>4;

  floatx4 acc[MT][NT] = {};

  for (int k = 0; k < K; k += 32) {
    __syncthreads();
    if (BM == 128 || wid < 4) load_lds16(ga0 + k, lA);
    load_lds16(gb0 + k, lB);
    __syncthreads();
    bf16x8 af[MT];
#pragma unroll
    for (int mt=0; mt<MT; ++mt)
      af[mt] = ldfrag(As, wm*(BM/2) + mt*16 + lr, lane);
#pragma unroll
    for (int nt=0; nt<NT; ++nt) {
      bf16x8 bfr = ldfrag(Bs, wn*(BN/4) + nt*16 + lr, lane);
#pragma unroll
      for (int mt=0; mt<MT; ++mt)
        acc[mt][nt] = __builtin_amdgcn_mfma_f32_16x16x32_bf16(af[mt], bfr, acc[mt][nt], 0, 0, 0);
    }
  }

#pragma unroll
  for (int nt=0; nt<NT; ++nt) {
    const int col = n0 + wn*(BN/4) + nt*16 + lr;
    if (col < ncmax) {
      const float bv = bias ? bias[col] : 0.f;
#pragma unroll
      for (int mt=0; mt<MT; ++mt) {
#pragma unroll
        for (int r=0; r<4; ++r) {
          const int row = m0 + wm*(BM/2) + mt*16 + lq*4 + r;
          C[(long long)row*ldc + col] = acc[mt][nt][r] + bv;
        }
      }
    }
  }
}

// ---------------------------------------------------------------------------
// Fused scores + top-k + softmax, v4 (unchanged).
// ---------------------------------------------------------------------------
__global__ __launch_bounds__(1024, 8) void score_topk(
    const u16* __restrict__ qF,   // [z][64][6][64][8]
    const u16* __restrict__ kxF,  // [z][80][6][64][8]
    u16* __restrict__ P)          // [z][1024][1184]
{
  constexpr int SROW = 1156;
  __shared__ float sm[16*SROW];   // 73,984 B -> 2 blocks/CU
  const int tid = threadIdx.x, wid = tid>>6, lane = tid&63;
  const int L = blockIdx.x;
  const int z  = (L & 7) + ((L >> 9) << 3);
  const int mt = (L >> 3) & 63;
  const int m0 = mt*16;
  const int lr = lane&15, lq = lane>>4;

  const u16* Aq = qF + (((long long)z*64 + mt)*6*64 + lane)*8;
  const u16* Bq = kxF + ((long long)z*80*6*64 + lane)*8;

  bf16x8 af[6];
#pragma unroll
  for (int kc=0;kc<6;++kc) af[kc] = *(const bf16x8*)(Aq + kc*512);

  const int base = wid*5;
  {
    floatx4 acc[5];
#pragma unroll
    for (int t=0;t<5;++t) acc[t] = floatx4{0.f,0.f,0.f,0.f};
#pragma unroll
    for (int t=0;t<5;++t){
      if (base + t < 73){
        const u16* bp = Bq + (long long)(base+t)*3072;   // 6*512
        bf16x8 b0 = *(const bf16x8*)(bp);
        bf16x8 b1 = *(const bf16x8*)(bp + 512);
        bf16x8 b2 = *(const bf16x8*)(bp + 1024);
        bf16x8 b3 = *(const bf16x8*)(bp + 1536);
        bf16x8 b4 = *(const bf16x8*)(bp + 2048);
        bf16x8 b5 = *(const bf16x8*)(bp + 2560);
        acc[t] = __builtin_amdgcn_mfma_f32_16x16x32_bf16(af[0], b0, acc[t], 0, 0, 0);
        acc[t] = __builtin_amdgcn_mfma_f32_16x16x32_bf16(af[1], b1, acc[t], 0, 0, 0);
        acc[t] = __builtin_amdgcn_mfma_f32_16x16x32_bf16(af[2], b2, acc[t], 0, 0, 0);
        acc[t] = __builtin_amdgcn_mfma_f32_16x16x32_bf16(af[3], b3, acc[t], 0, 0, 0);
        acc[t] = __builtin_amdgcn_mfma_f32_16x16x32_bf16(af[4], b4, acc[t], 0, 0, 0);
        acc[t] = __builtin_amdgcn_mfma_f32_16x16x32_bf16(af[5], b5, acc[t], 0, 0, 0);
      }
    }
#pragma unroll
    for (int t=0;t<5;++t){
      if (base + t < 73){
        const int col = (base+t)*16 + lr;
        if (col < 1153){
#pragma unroll
          for (int r=0;r<4;++r) sm[(lq*4+r)*SROW + col] = acc[t][r];
        }
      }
    }
  }
  __syncthreads();

  {
    const int row = wid;
    const int i = m0 + row;
    float* R = sm + row*SROW;

    float v[16];
#pragma unroll
    for (int x=0;x<8;++x){
      float2 f = *(const float2*)(R + x*128 + lane*2);
      v[2*x] = f.x; v[2*x+1] = f.y;
    }
#pragma unroll
    for (int x=0;x<16;++x){
      const int j = (x>>1)*128 + lane*2 + (x&1);
      int dl = i - j; dl = dl > 64 ? 64 : (dl < -64 ? -64 : dl);
      v[x] += R[1024 + dl + 64];
    }
    u32 u[16];
#pragma unroll
    for (int x=0;x<16;++x){
      u32 bb = __float_as_uint(v[x]);
      u[x] = bb ^ ((u32)((int)bb >> 31) | 0x80000000u);
    }
    u32 thr = 0;
#pragma unroll 1
    for (int bit=31; bit>=0; --bit){
      const u32 cand = thr | (1u<<bit);
      int c = 0;
#pragma unroll
      for (int x=0;x<16;++x) c += __popcll(__ballot(u[x] >= cand));
      if (c == 256){
        u32 mn = 0xFFFFFFFFu;
#pragma unroll
        for (int x=0;x<16;++x) if (u[x] >= cand && u[x] < mn) mn = u[x];
        for (int o=32;o;o>>=1){ u32 t = __shfl_xor(mn, o); mn = t < mn ? t : mn; }
        thr = mn;
        break;
      }
      if (c > 256) thr = cand;
    }
    float m = -3.0e38f;
#pragma unroll
    for (int x=0;x<16;++x) m = fmaxf(m, v[x]);
    for (int o=32;o;o>>=1) m = fmaxf(m, __shfl_xor(m, o));
    float e[16]; float Z = 0.f;
#pragma unroll
    for (int x=0;x<16;++x){
      e[x] = (u[x] >= thr) ? __expf(v[x]-m) : 0.f;
      Z += e[x];
    }
    for (int o=32;o;o>>=1) Z += __shfl_xor(Z, o);
    const float rz = 1.f / Z;

    u16* Pr = P + ((long long)z*1024 + i)*1184;
    u32* Pr32 = (u32*)Pr;
    float s0 = 0.f, s1 = 0.f;
#pragma unroll
    for (int x=0;x<8;++x){
      const float p0 = e[2*x]*rz, p1 = e[2*x+1]*rz;
      *(float2*)(R + x*128 + lane*2) = float2{p0, p1};
      Pr32[x*64 + lane] = cvt_pk_bf16(p0, p1);
      const int j0 = x*128 + lane*2;
      if (j0     >= i+64) s0 += p0;     // dist bucket t=0
      if (j0     <= i-64) s1 += p0;     // dist bucket t=128
      if (j0 + 1 >= i+64) s0 += p1;
      if (j0 + 1 <= i-64) s1 += p1;
    }
    for (int o=32;o;o>>=1){ s0 += __shfl_xor(s0,o); s1 += __shfl_xor(s1,o); }
    {
      const int t = lane + 1;        // 1..64
      const int j = i + 64 - t;
      const float wv = (j>=0 && j<1024) ? R[j] : 0.f;
      Pr[1024 + t] = f2bf(wv);
      if (lane < 63){
        const int t2 = lane + 65;    // 65..127
        const int j2 = i + 64 - t2;
        const float wv2 = (j2>=0 && j2<1024) ? R[j2] : 0.f;
        Pr[1024 + t2] = f2bf(wv2);
      }
      if (lane == 0){ Pr[1024] = f2bf(s0); Pr[1152] = f2bf(s1); }
      if (lane >= 33) Pr[1120 + lane] = 0;  // zero cols 1153..1183
    }
  }
}

// ---------------------------------------------------------------------------
// Elementwise prep kernels
// ---------------------------------------------------------------------------
__global__ __launch_bounds__(256) void planeize(const float* __restrict__ src, u16* __restrict__ dst,
                                                int total, int modeB){
  int idx = blockIdx.x*256 + threadIdx.x;
  if (idx >= total) return;
  int c = idx & 1023, r = idx >> 10;
  float v = src[idx];
  u16 hi = f2bf(v); u16 lo = f2bf(v - bf2f(hi));
  u16* d = dst + (long long)r*3072 + c;
  if (modeB){ d[0]=hi; d[1024]=hi; d[2048]=lo; }
  else      { d[0]=hi; d[1024]=lo; d[2048]=hi; }
}

// qkv -> qF (A planes hi|lo|hi) and kxF rows 0..1023 (B planes hi|hi|lo, k*0.125),
// both in MFMA-fragment-swizzled layout.
__global__ __launch_bounds__(256) void build_qk(const float* __restrict__ qkv,
                                                u16* __restrict__ qF, u16* __restrict__ kxF){
  int idx = blockIdx.x*256 + threadIdx.x;   // ((b*16+h)*1024+n)*64+d
  int d = idx & 63, n = (idx>>6) & 1023, bh = idx >> 16;
  int b = bh >> 4, h = bh & 15;
  long long src = (long long)(b*1024 + n)*3072 + h*64 + d;
  float qv = qkv[src];
  float kv = qkv[src + 1024] * 0.125f;
  u16 qhi=f2bf(qv), qlo=f2bf(qv - bf2f(qhi));
  u16 khi=f2bf(kv), klo=f2bf(kv - bf2f(khi));
  const int lane = (n&15) + (((d&31)>>3)<<4);
  const int elem = d&7, kc0 = d>>5;
  u16* q = qF + ((((long long)bh*64 + (n>>4))*6*64) + lane)*8 + elem;
  q[(kc0+0)*512] = qhi; q[(kc0+2)*512] = qlo; q[(kc0+4)*512] = qhi;
  u16* kx = kxF + ((((long long)bh*80 + (n>>4))*6*64) + lane)*8 + elem;
  kx[(kc0+0)*512] = khi; kx[(kc0+2)*512] = khi; kx[(kc0+4)*512] = klo;
}

// kxF rows 1024..1279: rel_k_emb planes (B-mode), zero pad rows; swizzled.
__global__ __launch_bounds__(256) void build_kxrel(const float* __restrict__ relk, u16* __restrict__ kxF){
  int idx = blockIdx.x*256 + threadIdx.x;   // (bh, t:256, d:64)
  int d = idx & 63, t = (idx>>6) & 255, bh = idx >> 14;
  u16 hi=0, lo=0;
  if (t < 129){ float v = relk[t*64 + d]; hi = f2bf(v); lo = f2bf(v - bf2f(hi)); }
  const int nrow = 1024 + t;
  const int lane = (t&15) + (((d&31)>>3)<<4);
  const int elem = d&7, kc0 = d>>5;
  u16* kx = kxF + ((((long long)bh*80 + (nrow>>4))*6*64) + lane)*8 + elem;
  kx[(kc0+0)*512] = hi; kx[(kc0+2)*512] = hi; kx[(kc0+4)*512] = lo;
}

__global__ __launch_bounds__(256) void build_vT(const float* __restrict__ qkv, u16* __restrict__ vA){
  __shared__ float tb[64][65];
  int bh = blockIdx.x >> 4, ntile = blockIdx.x & 15;
  int b = bh >> 4, h = bh & 15;
  int tid = threadIdx.x;
  int nl = tid >> 2, dc = (tid & 3)*16;
  const float* sp = qkv + (long long)(b*1024 + ntile*64 + nl)*3072 + 2048 + h*64 + dc;
#pragma unroll
  for (int j=0;j<16;j+=4){
    float4 f = *(const float4*)(sp + j);
    tb[dc+j+0][nl]=f.x; tb[dc+j+1][nl]=f.y; tb[dc+j+2][nl]=f.z; tb[dc+j+3][nl]=f.w;
  }
  __syncthreads();
  int d = tid >> 2, nc = (tid & 3)*16;
  u16* dp = vA + ((long long)bh*64 + d)*1184 + ntile*64 + nc;
#pragma unroll
  for (int j=0;j<16;j+=8){
    u16 a0=f2bf(tb[d][nc+j+0]), a1=f2bf(tb[d][nc+j+1]), a2=f2bf(tb[d][nc+j+2]), a3=f2bf(tb[d][nc+j+3]);
    u16 a4=f2bf(tb[d][nc+j+4]), a5=f2bf(tb[d][nc+j+5]), a6=f2bf(tb[d][nc+j+6]), a7=f2bf(tb[d][nc+j+7]);
    uint4 uu; uu.x=a0|((u32)a1<<16); uu.y=a2|((u32)a3<<16); uu.z=a4|((u32)a5<<16); uu.w=a6|((u32)a7<<16);
    *(uint4*)(dp + j) = uu;
  }
}

__global__ __launch_bounds__(256) void build_vText(const float* __restrict__ relv, u16* __restrict__ vA){
  int idx = blockIdx.x*256 + threadIdx.x;   // (bh, d, t:160)
  int t = idx % 160; int rest = idx / 160; int d = rest & 63; int bh = rest >> 6;
  u16 hv = 0;
  if (t < 129) hv = f2bf(relv[t*64 + d]);
  vA[((long long)bh*64 + d)*1184 + 1024 + t] = hv;
}

__global__ __launch_bounds__(256) void build_resS(const float* __restrict__ res, u16* __restrict__ resS){
  int idx = blockIdx.x*256 + threadIdx.x;
  int d = idx & 63, n = (idx>>6) & 1023, bh = idx >> 16;
  int b = bh >> 4, h = bh & 15;
  float v = res[idx];
  u16 hi = f2bf(v), lo = f2bf(v - bf2f(hi));
  u16* p = resS + (long long)(b*1024 + n)*3072 + h*64 + d;
  p[0]=hi; p[1024]=lo; p[2048]=hi;
}

// ---------------------------------------------------------------------------
extern "C" void kernel_launch(void* const* d_in, const int* in_sizes, int n_in,
                              void* d_out, int out_size, void* d_ws, size_t ws_size,
                              hipStream_t stream) {
  const float* x    = (const float*)d_in[0];
  const float* Wqkv = (const float*)d_in[1];
  const float* bqkv = (const float*)d_in[2];
  const float* Wout = (const float*)d_in[3];
  const float* bout = (const float*)d_in[4];
  const float* relk = (const float*)d_in[5];
  const float* relv = (const float*)d_in[6];
  const float* araw = (const float*)d_in[7];
  float* out = (float*)d_out;

  char* w = (char*)d_ws;
  size_t off = 0;
  auto take = [&](size_t bytes)->char*{ char* p = w + off; off += (bytes + 255) & ~(size_t)255; return p; };

  // regionA (90 MB): phase1 {xS|wqS|qkv32} -> per-half P (77.6 MB) -> {resS|woS}
  char* regionA = take(94371840);
  u16*   xS    = (u16*)  (regionA);
  u16*   wqS   = (u16*)  (regionA + 25165824);
  float* qkv32 = (float*)(regionA + 44040192);
  u16*   Ph    = (u16*)  (regionA);         // [32][1024][1184] u16 per half
  u16*   resS  = (u16*)  (regionA);
  u16*   woS   = (u16*)  (regionA + 25165824);
  u16*   qF    = (u16*)take(25165824);      // [64][64][6][64][8]
  u16*   kxF   = (u16*)take(31457280);      // [64][80][6][64][8]
  u16*   vA    = (u16*)take(9699328);       // [64][64][1184]
  u16*   vB    = (u16*)take(9699328);
  float* res   = (float*)take(16777216);    // [64][1024][64]
  (void)ws_size; (void)in_sizes; (void)n_in; (void)out_size;
  // total ~187 MiB

  // phase 1: QKV projection. qk at split-fp32 (K=3072 planes); v hi*hi (K=1024).
  planeize<<<16384,256,0,stream>>>(x,    xS,  4194304, 0);
  planeize<<<12288,256,0,stream>>>(Wqkv, wqS, 3145728, 1);
  gemm8<128,128><<<dim3(16,32,1),512,0,stream>>>(xS, wqS, qkv32, bqkv,
      3072, 3072, 3072, 3072, 2048);
  gemm8<128,128><<<dim3(8,32,1),512,0,stream>>>(xS, wqS + (long long)2048*3072,
      qkv32 + 2048, bqkv + 2048, 1024, 3072, 3072, 3072, 1024);
  build_qk   <<<16384,256,0,stream>>>(qkv32, qF, kxF);
  build_kxrel<<<4096, 256,0,stream>>>(relk, kxF);
  build_vT   <<<1024, 256,0,stream>>>(qkv32, vA);
  build_vText<<<2560, 256,0,stream>>>(relv, vA);

  // phases 2+3 per 32-head half: fused scores/topk/softmax -> P, then 3x AV
  // (AV = proven round-1 MODE-1 gemm_bt path)
  for (int half = 0; half < 2; ++half) {
    const long long zo = (long long)half * 32;
    score_topk<<<2048,1024,0,stream>>>(qF + zo*196608, kxF + zo*245760, Ph);
    gemm_bt<64,64,1><<<dim3(1,16,32),256,0,stream>>>(Ph, vA + zo*75776, nullptr, nullptr,
        1184, 1184, 1184, 0, 0, 1212416LL, 75776LL, 0LL,
        vB + zo*75776, res + zo*65536, araw, 0, 0);
    gemm_bt<64,64,1><<<dim3(1,16,32),256,0,stream>>>(Ph, vB + zo*75776, nullptr, nullptr,
        1024, 1184, 1184, 0, 0, 1212416LL, 75776LL, 0LL,
        vA + zo*75776, res + zo*65536, araw, 1, 1);
    gemm_bt<64,64,1><<<dim3(1,16,32),256,0,stream>>>(Ph, vA + zo*75776, nullptr, nullptr,
        1024, 1184, 1184, 0, 0, 1212416LL, 75776LL, 0LL,
        vB + zo*75776, res + zo*65536, araw, 2, 1);
  }

  // output projection (fp32 via split planes), 8-wave
  build_resS<<<16384,256,0,stream>>>(res, resS);
  planeize  <<<4096, 256,0,stream>>>(Wout, woS, 1048576, 1);
  gemm8<64,128><<<dim3(8,64,1),512,0,stream>>>(resS, woS, out, bout,
      3072, 3072, 3072, 1024, 1024);
}

// Round 6
// 589.253 us; speedup vs baseline: 1.2675x; 1.0122x over previous
//
#include <hip/hip_runtime.h>

typedef unsigned short u16;
typedef unsigned int   u32;
typedef unsigned long long u64;
typedef __bf16 bf16x8 __attribute__((ext_vector_type(8)));
typedef float  floatx4 __attribute__((ext_vector_type(4)));

#define DEV static __device__ __forceinline__

DEV u16 f2bf(float f){ u32 x = __float_as_uint(f); return (u16)((x + 0x7fffu + ((x>>16)&1u)) >> 16); }
DEV float bf2f(u16 h){ return __uint_as_float(((u32)h)<<16); }
// pack two f32 -> two bf16 (RNE), one instruction. dst.lo=cvt(a), dst.hi=cvt(b)
DEV u32 cvt_pk_bf16(float a, float b){ u32 r; asm("v_cvt_pk_bf16_f32 %0, %1, %2" : "=v"(r) : "v"(a), "v"(b)); return r; }

DEV void load_lds16(const u16* g, u16* l){
  __builtin_amdgcn_global_load_lds((const __attribute__((address_space(1))) u32*)g,
                                   (__attribute__((address_space(3))) u32*)l, 16, 0, 0);
}

// ---------------------------------------------------------------------------
// LDS swizzle for [rows][32 u16] tiles (verified bijective, rounds 2-5).
// Read: byte ^= (row&7)<<4. Staging: LDS dest linear, global source byte =
// unswz64(linear dest byte) (row-count agnostic: bits 9+ pass through).
// ---------------------------------------------------------------------------
DEV u32 unswz64(u32 p){
  u32 r0 = ((p>>6) ^ (p>>8)) & 1u;
  u32 b4 = ((p>>4) & 1u) ^ r0;
  u32 b5 = ((p>>5) ^ (p>>7)) & 1u;
  return (p & ~0x70u) | (b4<<4) | (b5<<5) | (r0<<6);
}
DEV bf16x8 ldfrag(const u16* base, int row, int lane){
  u32 off = ((u32)row<<6) + (((u32)lane>>4)<<4);
  off ^= (u32)(row&7)<<4;
  return *(const bf16x8*)((const char*)base + off);
}

// ---------------------------------------------------------------------------
// gemm8: 512-thread 8-wave MODE-0 GEMM (validated round 5: fixed the 2-phase
// drain's TLP starvation — 4 waves/SIMD vs gemm_bt's 2). 8 waves as 2(m)x4(n),
// ONE global_load_lds issue per operand per k-step. K ascending, one mfma per
// k-step per output -> bit-identical C.
// ---------------------------------------------------------------------------
template<int BM, int BN>
__global__ __launch_bounds__(512, 4) void gemm8(
    const u16* __restrict__ A, const u16* __restrict__ Bm, float* __restrict__ C,
    const float* __restrict__ bias, int K, int lda, int ldb, int ldc, int ncmax)
{
  constexpr int MT = (BM/2)/16;           // 4 (BM=128) or 2 (BM=64)
  constexpr int NT = (BN/4)/16;           // 2 (BN=128)
  __shared__ u16 As[BM*32];
  __shared__ u16 Bs[BN*32];

  const int tid = threadIdx.x, wid = tid>>6, lane = tid&63;
  const int m0 = blockIdx.y * BM, n0 = blockIdx.x * BN;

  const u32 g = unswz64((u32)tid*16);
  const int srow = g>>6, schunk = (g&63)>>1;
  const u16* ga0 = A  + (long long)(m0 + srow)*lda + schunk;  // used iff wid < BM/16
  const u16* gb0 = Bm + (long long)(n0 + srow)*ldb + schunk;

  u16* lA = As + (wid<<9);               // wave-uniform base: wave w -> rows 16w..16w+15
  u16* lB = Bs + (wid<<9);

  const int wm = wid>>2, wn = wid&3;
  const int lr = lane&15, lq = lane>>4;

  floatx4 acc[MT][NT] = {};

  for (int k = 0; k < K; k += 32) {
    __syncthreads();
    if (BM == 128 || wid < 4) load_lds16(ga0 + k, lA);
    load_lds16(gb0 + k, lB);
    __syncthreads();
    bf16x8 af[MT];
#pragma unroll
    for (int mt=0; mt<MT; ++mt)
      af[mt] = ldfrag(As, wm*(BM/2) + mt*16 + lr, lane);
#pragma unroll
    for (int nt=0; nt<NT; ++nt) {
      bf16x8 bfr = ldfrag(Bs, wn*(BN/4) + nt*16 + lr, lane);
#pragma unroll
      for (int mt=0; mt<MT; ++mt)
        acc[mt][nt] = __builtin_amdgcn_mfma_f32_16x16x32_bf16(af[mt], bfr, acc[mt][nt], 0, 0, 0);
    }
  }

#pragma unroll
  for (int nt=0; nt<NT; ++nt) {
    const int col = n0 + wn*(BN/4) + nt*16 + lr;
    if (col < ncmax) {
      const float bv = bias ? bias[col] : 0.f;
#pragma unroll
      for (int mt=0; mt<MT; ++mt) {
#pragma unroll
        for (int r=0; r<4; ++r) {
          const int row = m0 + wm*(BM/2) + mt*16 + lq*4 + r;
          C[(long long)row*ldc + col] = acc[mt][nt][r] + bv;
        }
      }
    }
  }
}

// ---------------------------------------------------------------------------
// av8: AV GEMM with MODE-1 epilogue, gemm8 structure (round-5 post-mortem:
// the 4-wave gemm_bt AV ran 2 waves/SIMD at 512 blocks -> ~50% of achievable
// BW; gemm8's 8-wave restructure just fixed the same defect on QKV).
// BM=64, BN=64 (all d), 8 waves as 2(m)x4(n): MT=2, NT=1. Staging: waves 0-3
// stage the P tile (16 rows each), waves 4-7 the V tile — identical linear-
// dest/inverse-swizzled-source map as gemm8 BM=64. Linear 512-block grid with
// XCD decode (16 m-blocks of a z on one XCD -> V[z] fetched once per XCD L2).
// K ascending, one mfma per k-step per output -> bit-identical to the round-1
// AV path. Epilogue: res[z][i][d] (+)= alpha*C; vout[z][d][i] = bf16(C)^T via
// the 64x136 LDS transpose (smem reused), uint4 stores; wv=0 skips the dead
// vout write on the last order.
// ---------------------------------------------------------------------------
__global__ __launch_bounds__(512, 4) void av8(
    const u16* __restrict__ P,    // [z][1024][1184]
    const u16* __restrict__ V,    // [z][64][1184]
    u16* __restrict__ vout,       // [z][64][1184]
    float* __restrict__ resb,     // [z][1024][64]
    const float* __restrict__ araw, int K, int order, int accum, int wv)
{
  __shared__ u16 smem[8704];      // As 2048 u16 | Bs 2048 u16 ; then 64x136 transpose
  u16* As = smem;                 // [64][32]
  u16* Bs = smem + 2048;          // [64][32]

  const int tid = threadIdx.x, wid = tid>>6, lane = tid&63;
  const int L = blockIdx.x;
  const int z  = (L & 7) + ((L >> 7) << 3);   // 4 z per XCD, 16 m-blocks clustered
  const int m0 = ((L >> 3) & 15) * 64;
  const int lr = lane&15, lq = lane>>4;

  const int sw = wid & 3;
  const u32 g = unswz64((u32)(sw*1024 + lane*16));
  const int srow = g>>6, schunk = (g&63)>>1;
  const u16* gsrc = (wid < 4)
      ? P + (long long)z*1212416 + (long long)(m0 + srow)*1184 + schunk
      : V + (long long)z*75776   + (long long)srow*1184 + schunk;
  u16* ldst = (wid < 4) ? As + (sw<<9) : Bs + (sw<<9);

  const int wm = wid>>2, wn = wid&3;
  floatx4 acc[2] = {};

  for (int k = 0; k < K; k += 32) {
    __syncthreads();
    load_lds16(gsrc + k, ldst);
    __syncthreads();
    bf16x8 bfr = ldfrag(Bs, wn*16 + lr, lane);
#pragma unroll
    for (int mt=0; mt<2; ++mt){
      bf16x8 af = ldfrag(As, wm*32 + mt*16 + lr, lane);
      acc[mt] = __builtin_amdgcn_mfma_f32_16x16x32_bf16(af, bfr, acc[mt], 0, 0, 0);
    }
  }

  const int h = z & 15;
  const float alpha = 1.f/(1.f + __expf(-araw[order*16 + h]));
  float* rb = resb + (long long)z * 65536;    // res[z][1024][64]
  const int d = wn*16 + lr;                   // C col -> V/d row
  __syncthreads();                            // staging reads done before smem reuse
#pragma unroll
  for (int mt=0; mt<2; ++mt){
#pragma unroll
    for (int r=0; r<4; ++r){
      const int row = wm*32 + mt*16 + lq*4 + r;
      const float v = acc[mt][r];
      const long long ri = (long long)(m0+row)*64 + d;
      rb[ri] = accum ? (rb[ri] + alpha*v) : (alpha*v);
      smem[d*136 + row] = f2bf(v);
    }
  }
  __syncthreads();
  if (wv){
    const int dd = tid>>3, cc = (tid&7)*8;
    u16* vp = vout + (long long)z*75776 + (long long)dd*1184 + m0 + cc;
    const u16* sp = smem + dd*136 + cc;
    uint4 uu;
    uu.x = sp[0] | ((u32)sp[1]<<16);
    uu.y = sp[2] | ((u32)sp[3]<<16);
    uu.z = sp[4] | ((u32)sp[5]<<16);
    uu.w = sp[6] | ((u32)sp[7]<<16);
    *(uint4*)(vp) = uu;
  }
}

// ---------------------------------------------------------------------------
// Fused scores + top-k + softmax, v4 (unchanged).
// ---------------------------------------------------------------------------
__global__ __launch_bounds__(1024, 8) void score_topk(
    const u16* __restrict__ qF,   // [z][64][6][64][8]
    const u16* __restrict__ kxF,  // [z][80][6][64][8]
    u16* __restrict__ P)          // [z][1024][1184]
{
  constexpr int SROW = 1156;
  __shared__ float sm[16*SROW];   // 73,984 B -> 2 blocks/CU
  const int tid = threadIdx.x, wid = tid>>6, lane = tid&63;
  const int L = blockIdx.x;
  const int z  = (L & 7) + ((L >> 9) << 3);
  const int mt = (L >> 3) & 63;
  const int m0 = mt*16;
  const int lr = lane&15, lq = lane>>4;

  const u16* Aq = qF + (((long long)z*64 + mt)*6*64 + lane)*8;
  const u16* Bq = kxF + ((long long)z*80*6*64 + lane)*8;

  bf16x8 af[6];
#pragma unroll
  for (int kc=0;kc<6;++kc) af[kc] = *(const bf16x8*)(Aq + kc*512);

  const int base = wid*5;
  {
    floatx4 acc[5];
#pragma unroll
    for (int t=0;t<5;++t) acc[t] = floatx4{0.f,0.f,0.f,0.f};
#pragma unroll
    for (int t=0;t<5;++t){
      if (base + t < 73){
        const u16* bp = Bq + (long long)(base+t)*3072;   // 6*512
        bf16x8 b0 = *(const bf16x8*)(bp);
        bf16x8 b1 = *(const bf16x8*)(bp + 512);
        bf16x8 b2 = *(const bf16x8*)(bp + 1024);
        bf16x8 b3 = *(const bf16x8*)(bp + 1536);
        bf16x8 b4 = *(const bf16x8*)(bp + 2048);
        bf16x8 b5 = *(const bf16x8*)(bp + 2560);
        acc[t] = __builtin_amdgcn_mfma_f32_16x16x32_bf16(af[0], b0, acc[t], 0, 0, 0);
        acc[t] = __builtin_amdgcn_mfma_f32_16x16x32_bf16(af[1], b1, acc[t], 0, 0, 0);
        acc[t] = __builtin_amdgcn_mfma_f32_16x16x32_bf16(af[2], b2, acc[t], 0, 0, 0);
        acc[t] = __builtin_amdgcn_mfma_f32_16x16x32_bf16(af[3], b3, acc[t], 0, 0, 0);
        acc[t] = __builtin_amdgcn_mfma_f32_16x16x32_bf16(af[4], b4, acc[t], 0, 0, 0);
        acc[t] = __builtin_amdgcn_mfma_f32_16x16x32_bf16(af[5], b5, acc[t], 0, 0, 0);
      }
    }
#pragma unroll
    for (int t=0;t<5;++t){
      if (base + t < 73){
        const int col = (base+t)*16 + lr;
        if (col < 1153){
#pragma unroll
          for (int r=0;r<4;++r) sm[(lq*4+r)*SROW + col] = acc[t][r];
        }
      }
    }
  }
  __syncthreads();

  {
    const int row = wid;
    const int i = m0 + row;
    float* R = sm + row*SROW;

    float v[16];
#pragma unroll
    for (int x=0;x<8;++x){
      float2 f = *(const float2*)(R + x*128 + lane*2);
      v[2*x] = f.x; v[2*x+1] = f.y;
    }
#pragma unroll
    for (int x=0;x<16;++x){
      const int j = (x>>1)*128 + lane*2 + (x&1);
      int dl = i - j; dl = dl > 64 ? 64 : (dl < -64 ? -64 : dl);
      v[x] += R[1024 + dl + 64];
    }
    u32 u[16];
#pragma unroll
    for (int x=0;x<16;++x){
      u32 bb = __float_as_uint(v[x]);
      u[x] = bb ^ ((u32)((int)bb >> 31) | 0x80000000u);
    }
    u32 thr = 0;
#pragma unroll 1
    for (int bit=31; bit>=0; --bit){
      const u32 cand = thr | (1u<<bit);
      int c = 0;
#pragma unroll
      for (int x=0;x<16;++x) c += __popcll(__ballot(u[x] >= cand));
      if (c == 256){
        u32 mn = 0xFFFFFFFFu;
#pragma unroll
        for (int x=0;x<16;++x) if (u[x] >= cand && u[x] < mn) mn = u[x];
        for (int o=32;o;o>>=1){ u32 t = __shfl_xor(mn, o); mn = t < mn ? t : mn; }
        thr = mn;
        break;
      }
      if (c > 256) thr = cand;
    }
    float m = -3.0e38f;
#pragma unroll
    for (int x=0;x<16;++x) m = fmaxf(m, v[x]);
    for (int o=32;o;o>>=1) m = fmaxf(m, __shfl_xor(m, o));
    float e[16]; float Z = 0.f;
#pragma unroll
    for (int x=0;x<16;++x){
      e[x] = (u[x] >= thr) ? __expf(v[x]-m) : 0.f;
      Z += e[x];
    }
    for (int o=32;o;o>>=1) Z += __shfl_xor(Z, o);
    const float rz = 1.f / Z;

    u16* Pr = P + ((long long)z*1024 + i)*1184;
    u32* Pr32 = (u32*)Pr;
    float s0 = 0.f, s1 = 0.f;
#pragma unroll
    for (int x=0;x<8;++x){
      const float p0 = e[2*x]*rz, p1 = e[2*x+1]*rz;
      *(float2*)(R + x*128 + lane*2) = float2{p0, p1};
      Pr32[x*64 + lane] = cvt_pk_bf16(p0, p1);
      const int j0 = x*128 + lane*2;
      if (j0     >= i+64) s0 += p0;     // dist bucket t=0
      if (j0     <= i-64) s1 += p0;     // dist bucket t=128
      if (j0 + 1 >= i+64) s0 += p1;
      if (j0 + 1 <= i-64) s1 += p1;
    }
    for (int o=32;o;o>>=1){ s0 += __shfl_xor(s0,o); s1 += __shfl_xor(s1,o); }
    {
      const int t = lane + 1;        // 1..64
      const int j = i + 64 - t;
      const float wv = (j>=0 && j<1024) ? R[j] : 0.f;
      Pr[1024 + t] = f2bf(wv);
      if (lane < 63){
        const int t2 = lane + 65;    // 65..127
        const int j2 = i + 64 - t2;
        const float wv2 = (j2>=0 && j2<1024) ? R[j2] : 0.f;
        Pr[1024 + t2] = f2bf(wv2);
      }
      if (lane == 0){ Pr[1024] = f2bf(s0); Pr[1152] = f2bf(s1); }
      if (lane >= 33) Pr[1120 + lane] = 0;  // zero cols 1153..1183
    }
  }
}

// ---------------------------------------------------------------------------
// Elementwise prep kernels
// ---------------------------------------------------------------------------
__global__ __launch_bounds__(256) void planeize(const float* __restrict__ src, u16* __restrict__ dst,
                                                int total, int modeB){
  int idx = blockIdx.x*256 + threadIdx.x;
  if (idx >= total) return;
  int c = idx & 1023, r = idx >> 10;
  float v = src[idx];
  u16 hi = f2bf(v); u16 lo = f2bf(v - bf2f(hi));
  u16* d = dst + (long long)r*3072 + c;
  if (modeB){ d[0]=hi; d[1024]=hi; d[2048]=lo; }
  else      { d[0]=hi; d[1024]=lo; d[2048]=hi; }
}

// qkv -> qF (A planes hi|lo|hi) and kxF rows 0..1023 (B planes hi|hi|lo, k*0.125),
// both in MFMA-fragment-swizzled layout.
__global__ __launch_bounds__(256) void build_qk(const float* __restrict__ qkv,
                                                u16* __restrict__ qF, u16* __restrict__ kxF){
  int idx = blockIdx.x*256 + threadIdx.x;   // ((b*16+h)*1024+n)*64+d
  int d = idx & 63, n = (idx>>6) & 1023, bh = idx >> 16;
  int b = bh >> 4, h = bh & 15;
  long long src = (long long)(b*1024 + n)*3072 + h*64 + d;
  float qv = qkv[src];
  float kv = qkv[src + 1024] * 0.125f;
  u16 qhi=f2bf(qv), qlo=f2bf(qv - bf2f(qhi));
  u16 khi=f2bf(kv), klo=f2bf(kv - bf2f(khi));
  const int lane = (n&15) + (((d&31)>>3)<<4);
  const int elem = d&7, kc0 = d>>5;
  u16* q = qF + ((((long long)bh*64 + (n>>4))*6*64) + lane)*8 + elem;
  q[(kc0+0)*512] = qhi; q[(kc0+2)*512] = qlo; q[(kc0+4)*512] = qhi;
  u16* kx = kxF + ((((long long)bh*80 + (n>>4))*6*64) + lane)*8 + elem;
  kx[(kc0+0)*512] = khi; kx[(kc0+2)*512] = khi; kx[(kc0+4)*512] = klo;
}

// kxF rows 1024..1279: rel_k_emb planes (B-mode), zero pad rows; swizzled.
__global__ __launch_bounds__(256) void build_kxrel(const float* __restrict__ relk, u16* __restrict__ kxF){
  int idx = blockIdx.x*256 + threadIdx.x;   // (bh, t:256, d:64)
  int d = idx & 63, t = (idx>>6) & 255, bh = idx >> 14;
  u16 hi=0, lo=0;
  if (t < 129){ float v = relk[t*64 + d]; hi = f2bf(v); lo = f2bf(v - bf2f(hi)); }
  const int nrow = 1024 + t;
  const int lane = (t&15) + (((d&31)>>3)<<4);
  const int elem = d&7, kc0 = d>>5;
  u16* kx = kxF + ((((long long)bh*80 + (nrow>>4))*6*64) + lane)*8 + elem;
  kx[(kc0+0)*512] = hi; kx[(kc0+2)*512] = hi; kx[(kc0+4)*512] = lo;
}

__global__ __launch_bounds__(256) void build_vT(const float* __restrict__ qkv, u16* __restrict__ vA){
  __shared__ float tb[64][65];
  int bh = blockIdx.x >> 4, ntile = blockIdx.x & 15;
  int b = bh >> 4, h = bh & 15;
  int tid = threadIdx.x;
  int nl = tid >> 2, dc = (tid & 3)*16;
  const float* sp = qkv + (long long)(b*1024 + ntile*64 + nl)*3072 + 2048 + h*64 + dc;
#pragma unroll
  for (int j=0;j<16;j+=4){
    float4 f = *(const float4*)(sp + j);
    tb[dc+j+0][nl]=f.x; tb[dc+j+1][nl]=f.y; tb[dc+j+2][nl]=f.z; tb[dc+j+3][nl]=f.w;
  }
  __syncthreads();
  int d = tid >> 2, nc = (tid & 3)*16;
  u16* dp = vA + ((long long)bh*64 + d)*1184 + ntile*64 + nc;
#pragma unroll
  for (int j=0;j<16;j+=8){
    u16 a0=f2bf(tb[d][nc+j+0]), a1=f2bf(tb[d][nc+j+1]), a2=f2bf(tb[d][nc+j+2]), a3=f2bf(tb[d][nc+j+3]);
    u16 a4=f2bf(tb[d][nc+j+4]), a5=f2bf(tb[d][nc+j+5]), a6=f2bf(tb[d][nc+j+6]), a7=f2bf(tb[d][nc+j+7]);
    uint4 uu; uu.x=a0|((u32)a1<<16); uu.y=a2|((u32)a3<<16); uu.z=a4|((u32)a5<<16); uu.w=a6|((u32)a7<<16);
    *(uint4*)(dp + j) = uu;
  }
}

__global__ __launch_bounds__(256) void build_vText(const float* __restrict__ relv, u16* __restrict__ vA){
  int idx = blockIdx.x*256 + threadIdx.x;   // (bh, d, t:160)
  int t = idx % 160; int rest = idx / 160; int d = rest & 63; int bh = rest >> 6;
  u16 hv = 0;
  if (t < 129) hv = f2bf(relv[t*64 + d]);
  vA[((long long)bh*64 + d)*1184 + 1024 + t] = hv;
}

__global__ __launch_bounds__(256) void build_resS(const float* __restrict__ res, u16* __restrict__ resS){
  int idx = blockIdx.x*256 + threadIdx.x;
  int d = idx & 63, n = (idx>>6) & 1023, bh = idx >> 16;
  int b = bh >> 4, h = bh & 15;
  float v = res[idx];
  u16 hi = f2bf(v), lo = f2bf(v - bf2f(hi));
  u16* p = resS + (long long)(b*1024 + n)*3072 + h*64 + d;
  p[0]=hi; p[1024]=lo; p[2048]=hi;
}

// ---------------------------------------------------------------------------
extern "C" void kernel_launch(void* const* d_in, const int* in_sizes, int n_in,
                              void* d_out, int out_size, void* d_ws, size_t ws_size,
                              hipStream_t stream) {
  const float* x    = (const float*)d_in[0];
  const float* Wqkv = (const float*)d_in[1];
  const float* bqkv = (const float*)d_in[2];
  const float* Wout = (const float*)d_in[3];
  const float* bout = (const float*)d_in[4];
  const float* relk = (const float*)d_in[5];
  const float* relv = (const float*)d_in[6];
  const float* araw = (const float*)d_in[7];
  float* out = (float*)d_out;

  char* w = (char*)d_ws;
  size_t off = 0;
  auto take = [&](size_t bytes)->char*{ char* p = w + off; off += (bytes + 255) & ~(size_t)255; return p; };

  // regionA (90 MB): phase1 {xS|wqS|qkv32} -> per-half P (77.6 MB) -> {resS|woS}
  char* regionA = take(94371840);
  u16*   xS    = (u16*)  (regionA);
  u16*   wqS   = (u16*)  (regionA + 25165824);
  float* qkv32 = (float*)(regionA + 44040192);
  u16*   Ph    = (u16*)  (regionA);         // [32][1024][1184] u16 per half
  u16*   resS  = (u16*)  (regionA);
  u16*   woS   = (u16*)  (regionA + 25165824);
  u16*   qF    = (u16*)take(25165824);      // [64][64][6][64][8]
  u16*   kxF   = (u16*)take(31457280);      // [64][80][6][64][8]
  u16*   vA    = (u16*)take(9699328);       // [64][64][1184]
  u16*   vB    = (u16*)take(9699328);
  float* res   = (float*)take(16777216);    // [64][1024][64]
  (void)ws_size; (void)in_sizes; (void)n_in; (void)out_size;
  // total ~187 MiB

  // phase 1: QKV projection. qk at split-fp32 (K=3072 planes); v hi*hi (K=1024).
  planeize<<<16384,256,0,stream>>>(x,    xS,  4194304, 0);
  planeize<<<12288,256,0,stream>>>(Wqkv, wqS, 3145728, 1);
  gemm8<128,128><<<dim3(16,32,1),512,0,stream>>>(xS, wqS, qkv32, bqkv,
      3072, 3072, 3072, 3072, 2048);
  gemm8<128,128><<<dim3(8,32,1),512,0,stream>>>(xS, wqS + (long long)2048*3072,
      qkv32 + 2048, bqkv + 2048, 1024, 3072, 3072, 3072, 1024);
  build_qk   <<<16384,256,0,stream>>>(qkv32, qF, kxF);
  build_kxrel<<<4096, 256,0,stream>>>(relk, kxF);
  build_vT   <<<1024, 256,0,stream>>>(qkv32, vA);
  build_vText<<<2560, 256,0,stream>>>(relv, vA);

  // phases 2+3 per 32-head half: fused scores/topk/softmax -> P, then 3x AV
  for (int half = 0; half < 2; ++half) {
    const long long zo = (long long)half * 32;
    score_topk<<<2048,1024,0,stream>>>(qF + zo*196608, kxF + zo*245760, Ph);
    av8<<<512,512,0,stream>>>(Ph, vA + zo*75776, vB + zo*75776, res + zo*65536,
        araw, 1184, 0, 0, 1);
    av8<<<512,512,0,stream>>>(Ph, vB + zo*75776, vA + zo*75776, res + zo*65536,
        araw, 1024, 1, 1, 1);
    av8<<<512,512,0,stream>>>(Ph, vA + zo*75776, vB + zo*75776, res + zo*65536,
        araw, 1024, 2, 1, 0);
  }

  // output projection (fp32 via split planes), 8-wave
  build_resS<<<16384,256,0,stream>>>(res, resS);
  planeize  <<<4096, 256,0,stream>>>(Wout, woS, 1048576, 1);
  gemm8<64,128><<<dim3(8,64,1),512,0,stream>>>(resS, woS, out, bout,
      3072, 3072, 3072, 1024, 1024);
}

// Round 8
// 556.469 us; speedup vs baseline: 1.3422x; 1.0589x over previous
//
#include <hip/hip_runtime.h>

typedef unsigned short u16;
typedef unsigned int   u32;
typedef unsigned long long u64;
typedef __bf16 bf16x8 __attribute__((ext_vector_type(8)));
typedef float  floatx4 __attribute__((ext_vector_type(4)));

#define DEV static __device__ __forceinline__

DEV u16 f2bf(float f){ u32 x = __float_as_uint(f); return (u16)((x + 0x7fffu + ((x>>16)&1u)) >> 16); }
DEV float bf2f(u16 h){ return __uint_as_float(((u32)h)<<16); }
// pack two f32 -> two bf16 (RNE), one instruction. dst.lo=cvt(a), dst.hi=cvt(b)
DEV u32 cvt_pk_bf16(float a, float b){ u32 r; asm("v_cvt_pk_bf16_f32 %0, %1, %2" : "=v"(r) : "v"(a), "v"(b)); return r; }

DEV void load_lds16(const u16* g, u16* l){
  __builtin_amdgcn_global_load_lds((const __attribute__((address_space(1))) u32*)g,
                                   (__attribute__((address_space(3))) u32*)l, 16, 0, 0);
}

// Memory-fenced workgroup barrier for raw-pipeline use (rule #18: the bare
// s_barrier builtin is NOT a compiler memory fence — LDS reads / global_load_lds
// can be hoisted across it, which raced in round 7). The empty-asm clobbers pin
// all memory ops on their side of the barrier at IR level; sched_barrier(0)
// pins the machine scheduler.
DEV void barrier_fenced(){
  asm volatile("" ::: "memory");
  __builtin_amdgcn_sched_barrier(0);
  __builtin_amdgcn_s_barrier();
  __builtin_amdgcn_sched_barrier(0);
  asm volatile("" ::: "memory");
}

// ---------------------------------------------------------------------------
// LDS swizzle for [rows][32 u16] tiles (verified bijective, rounds 2-6).
// Read: byte ^= (row&7)<<4. Staging: LDS dest linear, global source byte =
// unswz64(linear dest byte) (row-count agnostic: bits 9+ pass through).
// ---------------------------------------------------------------------------
DEV u32 unswz64(u32 p){
  u32 r0 = ((p>>6) ^ (p>>8)) & 1u;
  u32 b4 = ((p>>4) & 1u) ^ r0;
  u32 b5 = ((p>>5) ^ (p>>7)) & 1u;
  return (p & ~0x70u) | (b4<<4) | (b5<<5) | (r0<<6);
}
DEV bf16x8 ldfrag(const u16* base, int row, int lane){
  u32 off = ((u32)row<<6) + (((u32)lane>>4)<<4);
  off ^= (u32)(row&7)<<4;
  return *(const bf16x8*)((const char*)base + off);
}

// ---------------------------------------------------------------------------
// gemm8: 512-thread 8-wave MODE-0 GEMM (validated round 5). 8 waves as
// 2(m)x4(n), ONE global_load_lds issue per operand per k-step. K ascending,
// one mfma per k-step per output -> bit-identical C.
// ---------------------------------------------------------------------------
template<int BM, int BN>
__global__ __launch_bounds__(512, 4) void gemm8(
    const u16* __restrict__ A, const u16* __restrict__ Bm, float* __restrict__ C,
    const float* __restrict__ bias, int K, int lda, int ldb, int ldc, int ncmax)
{
  constexpr int MT = (BM/2)/16;           // 4 (BM=128) or 2 (BM=64)
  constexpr int NT = (BN/4)/16;           // 2 (BN=128)
  __shared__ u16 As[BM*32];
  __shared__ u16 Bs[BN*32];

  const int tid = threadIdx.x, wid = tid>>6, lane = tid&63;
  const int m0 = blockIdx.y * BM, n0 = blockIdx.x * BN;

  const u32 g = unswz64((u32)tid*16);
  const int srow = g>>6, schunk = (g&63)>>1;
  const u16* ga0 = A  + (long long)(m0 + srow)*lda + schunk;  // used iff wid < BM/16
  const u16* gb0 = Bm + (long long)(n0 + srow)*ldb + schunk;

  u16* lA = As + (wid<<9);               // wave-uniform base: wave w -> rows 16w..16w+15
  u16* lB = Bs + (wid<<9);

  const int wm = wid>>2, wn = wid&3;
  const int lr = lane&15, lq = lane>>4;

  floatx4 acc[MT][NT] = {};

  for (int k = 0; k < K; k += 32) {
    __syncthreads();
    if (BM == 128 || wid < 4) load_lds16(ga0 + k, lA);
    load_lds16(gb0 + k, lB);
    __syncthreads();
    bf16x8 af[MT];
#pragma unroll
    for (int mt=0; mt<MT; ++mt)
      af[mt] = ldfrag(As, wm*(BM/2) + mt*16 + lr, lane);
#pragma unroll
    for (int nt=0; nt<NT; ++nt) {
      bf16x8 bfr = ldfrag(Bs, wn*(BN/4) + nt*16 + lr, lane);
#pragma unroll
      for (int mt=0; mt<MT; ++mt)
        acc[mt][nt] = __builtin_amdgcn_mfma_f32_16x16x32_bf16(af[mt], bfr, acc[mt][nt], 0, 0, 0);
    }
  }

#pragma unroll
  for (int nt=0; nt<NT; ++nt) {
    const int col = n0 + wn*(BN/4) + nt*16 + lr;
    if (col < ncmax) {
      const float bv = bias ? bias[col] : 0.f;
#pragma unroll
      for (int mt=0; mt<MT; ++mt) {
#pragma unroll
        for (int r=0; r<4; ++r) {
          const int row = m0 + wm*(BM/2) + mt*16 + lq*4 + r;
          C[(long long)row*ldc + col] = acc[mt][nt][r] + bv;
        }
      }
    }
  }
}

// ---------------------------------------------------------------------------
// av8 v2.1: counted-vmcnt ring pipeline (T3+T4), race-fixed. Round-7 raced
// because the bare s_barrier builtin is not a compiler memory fence: ds_reads
// hoisted above barrier-1 (guarded only by MY wave's vmcnt, not the other
// waves' loads) and/or stage() hoisted above barrier-2. v2.1 uses
// barrier_fenced() (asm memory clobbers + sched_barrier(0) around s_barrier)
// at both sync points — memory ops cannot cross in either direction.
// Structure unchanged: 8-buffer LDS ring (64 KB), per step
// { s_waitcnt vmcnt(7); BARRIER; 3 ds_read + 2 MFMA; BARRIER; stage(s+8) }.
// 7 x 8KB in flight per block spans ~HBM latency; no vmcnt(0) drain in loop.
// Tail: descending literal vmcnt (6..0). Staging map / ldfrag / k-ascending
// MFMA chain / epilogue byte-identical to round 6 -> bit-identical output.
// ---------------------------------------------------------------------------
__global__ __launch_bounds__(512, 4) void av8(
    const u16* __restrict__ P,    // [z][1024][1184]
    const u16* __restrict__ V,    // [z][64][1184]
    u16* __restrict__ vout,       // [z][64][1184]
    float* __restrict__ resb,     // [z][1024][64]
    const float* __restrict__ araw, int K, int order, int accum, int wv)
{
  __shared__ u16 smem[32768];     // 8 ring buffers x (As 2048 | Bs 2048) u16 = 64 KB
                                  // epilogue reuses [0..8704) as 64x136 transpose
  const int tid = threadIdx.x, wid = tid>>6, lane = tid&63;
  const int L = blockIdx.x;
  const int z  = (L & 7) + ((L >> 7) << 3);   // 4 z per XCD, 16 m-blocks clustered
  const int m0 = ((L >> 3) & 15) * 64;
  const int lr = lane&15, lq = lane>>4;

  const int sw = wid & 3;
  const u32 g = unswz64((u32)(sw*1024 + lane*16));
  const int srow = g>>6, schunk = (g&63)>>1;
  const u16* gsrc = (wid < 4)
      ? P + (long long)z*1212416 + (long long)(m0 + srow)*1184 + schunk
      : V + (long long)z*75776   + (long long)srow*1184 + schunk;
  const int bsel = (wid < 4) ? 0 : 2048;      // A half / B half of each ring buffer
  u16* ldst0 = smem + bsel + (sw<<9);         // wave-uniform LDS dest (+ c*4096)

  const int wm = wid>>2, wn = wid&3;
  const int wm32 = wm*32, wn16 = wn*16;
  const int nk = K >> 5;                      // 37 or 32 (always > 8)

  auto stage = [&](int p){ load_lds16(gsrc + (p<<5), ldst0 + ((p&7)<<12)); };

  floatx4 acc[2] = {};

#define AV_STEP(CC, VC) do { \
    asm volatile("s_waitcnt vmcnt(" VC ")" ::: "memory"); \
    barrier_fenced(); \
    const u16* Asc = smem + ((u32)(CC)<<12); \
    const u16* Bsc = Asc + 2048; \
    bf16x8 bfr = ldfrag(Bsc, wn16 + lr, lane); \
    bf16x8 af0 = ldfrag(Asc, wm32 + lr, lane); \
    bf16x8 af1 = ldfrag(Asc, wm32 + 16 + lr, lane); \
    acc[0] = __builtin_amdgcn_mfma_f32_16x16x32_bf16(af0, bfr, acc[0], 0, 0, 0); \
    acc[1] = __builtin_amdgcn_mfma_f32_16x16x32_bf16(af1, bfr, acc[1], 0, 0, 0); \
    barrier_fenced(); \
  } while(0)

#pragma unroll
  for (int p = 0; p < 8; ++p) stage(p);

  for (int s = 0; s < nk - 8; ++s){
    AV_STEP(s & 7, "7");
    stage(s + 8);                  // into buf (s+8)&7 == s&7, just freed by barrier-2
  }
  AV_STEP((nk-8) & 7, "7");
  AV_STEP((nk-7) & 7, "6");
  AV_STEP((nk-6) & 7, "5");
  AV_STEP((nk-5) & 7, "4");
  AV_STEP((nk-4) & 7, "3");
  AV_STEP((nk-3) & 7, "2");
  AV_STEP((nk-2) & 7, "1");
  AV_STEP((nk-1) & 7, "0");
#undef AV_STEP

  const int h = z & 15;
  const float alpha = 1.f/(1.f + __expf(-araw[order*16 + h]));
  float* rb = resb + (long long)z * 65536;    // res[z][1024][64]
  const int d = wn16 + lr;                    // C col -> V/d row
  __syncthreads();                            // ring reads done before smem reuse
#pragma unroll
  for (int mt=0; mt<2; ++mt){
#pragma unroll
    for (int r=0; r<4; ++r){
      const int row = wm32 + mt*16 + lq*4 + r;
      const float v = acc[mt][r];
      const long long ri = (long long)(m0+row)*64 + d;
      rb[ri] = accum ? (rb[ri] + alpha*v) : (alpha*v);
      smem[d*136 + row] = f2bf(v);
    }
  }
  __syncthreads();
  if (wv){
    const int dd = tid>>3, cc = (tid&7)*8;
    u16* vp = vout + (long long)z*75776 + (long long)dd*1184 + m0 + cc;
    const u16* sp = smem + dd*136 + cc;
    uint4 uu;
    uu.x = sp[0] | ((u32)sp[1]<<16);
    uu.y = sp[2] | ((u32)sp[3]<<16);
    uu.z = sp[4] | ((u32)sp[5]<<16);
    uu.w = sp[6] | ((u32)sp[7]<<16);
    *(uint4*)(vp) = uu;
  }
}

// ---------------------------------------------------------------------------
// Fused scores + top-k + softmax, v4 (unchanged).
// ---------------------------------------------------------------------------
__global__ __launch_bounds__(1024, 8) void score_topk(
    const u16* __restrict__ qF,   // [z][64][6][64][8]
    const u16* __restrict__ kxF,  // [z][80][6][64][8]
    u16* __restrict__ P)          // [z][1024][1184]
{
  constexpr int SROW = 1156;
  __shared__ float sm[16*SROW];   // 73,984 B -> 2 blocks/CU
  const int tid = threadIdx.x, wid = tid>>6, lane = tid&63;
  const int L = blockIdx.x;
  const int z  = (L & 7) + ((L >> 9) << 3);
  const int mt = (L >> 3) & 63;
  const int m0 = mt*16;
  const int lr = lane&15, lq = lane>>4;

  const u16* Aq = qF + (((long long)z*64 + mt)*6*64 + lane)*8;
  const u16* Bq = kxF + ((long long)z*80*6*64 + lane)*8;

  bf16x8 af[6];
#pragma unroll
  for (int kc=0;kc<6;++kc) af[kc] = *(const bf16x8*)(Aq + kc*512);

  const int base = wid*5;
  {
    floatx4 acc[5];
#pragma unroll
    for (int t=0;t<5;++t) acc[t] = floatx4{0.f,0.f,0.f,0.f};
#pragma unroll
    for (int t=0;t<5;++t){
      if (base + t < 73){
        const u16* bp = Bq + (long long)(base+t)*3072;   // 6*512
        bf16x8 b0 = *(const bf16x8*)(bp);
        bf16x8 b1 = *(const bf16x8*)(bp + 512);
        bf16x8 b2 = *(const bf16x8*)(bp + 1024);
        bf16x8 b3 = *(const bf16x8*)(bp + 1536);
        bf16x8 b4 = *(const bf16x8*)(bp + 2048);
        bf16x8 b5 = *(const bf16x8*)(bp + 2560);
        acc[t] = __builtin_amdgcn_mfma_f32_16x16x32_bf16(af[0], b0, acc[t], 0, 0, 0);
        acc[t] = __builtin_amdgcn_mfma_f32_16x16x32_bf16(af[1], b1, acc[t], 0, 0, 0);
        acc[t] = __builtin_amdgcn_mfma_f32_16x16x32_bf16(af[2], b2, acc[t], 0, 0, 0);
        acc[t] = __builtin_amdgcn_mfma_f32_16x16x32_bf16(af[3], b3, acc[t], 0, 0, 0);
        acc[t] = __builtin_amdgcn_mfma_f32_16x16x32_bf16(af[4], b4, acc[t], 0, 0, 0);
        acc[t] = __builtin_amdgcn_mfma_f32_16x16x32_bf16(af[5], b5, acc[t], 0, 0, 0);
      }
    }
#pragma unroll
    for (int t=0;t<5;++t){
      if (base + t < 73){
        const int col = (base+t)*16 + lr;
        if (col < 1153){
#pragma unroll
          for (int r=0;r<4;++r) sm[(lq*4+r)*SROW + col] = acc[t][r];
        }
      }
    }
  }
  __syncthreads();

  {
    const int row = wid;
    const int i = m0 + row;
    float* R = sm + row*SROW;

    float v[16];
#pragma unroll
    for (int x=0;x<8;++x){
      float2 f = *(const float2*)(R + x*128 + lane*2);
      v[2*x] = f.x; v[2*x+1] = f.y;
    }
#pragma unroll
    for (int x=0;x<16;++x){
      const int j = (x>>1)*128 + lane*2 + (x&1);
      int dl = i - j; dl = dl > 64 ? 64 : (dl < -64 ? -64 : dl);
      v[x] += R[1024 + dl + 64];
    }
    u32 u[16];
#pragma unroll
    for (int x=0;x<16;++x){
      u32 bb = __float_as_uint(v[x]);
      u[x] = bb ^ ((u32)((int)bb >> 31) | 0x80000000u);
    }
    u32 thr = 0;
#pragma unroll 1
    for (int bit=31; bit>=0; --bit){
      const u32 cand = thr | (1u<<bit);
      int c = 0;
#pragma unroll
      for (int x=0;x<16;++x) c += __popcll(__ballot(u[x] >= cand));
      if (c == 256){
        u32 mn = 0xFFFFFFFFu;
#pragma unroll
        for (int x=0;x<16;++x) if (u[x] >= cand && u[x] < mn) mn = u[x];
        for (int o=32;o;o>>=1){ u32 t = __shfl_xor(mn, o); mn = t < mn ? t : mn; }
        thr = mn;
        break;
      }
      if (c > 256) thr = cand;
    }
    float m = -3.0e38f;
#pragma unroll
    for (int x=0;x<16;++x) m = fmaxf(m, v[x]);
    for (int o=32;o;o>>=1) m = fmaxf(m, __shfl_xor(m, o));
    float e[16]; float Z = 0.f;
#pragma unroll
    for (int x=0;x<16;++x){
      e[x] = (u[x] >= thr) ? __expf(v[x]-m) : 0.f;
      Z += e[x];
    }
    for (int o=32;o;o>>=1) Z += __shfl_xor(Z, o);
    const float rz = 1.f / Z;

    u16* Pr = P + ((long long)z*1024 + i)*1184;
    u32* Pr32 = (u32*)Pr;
    float s0 = 0.f, s1 = 0.f;
#pragma unroll
    for (int x=0;x<8;++x){
      const float p0 = e[2*x]*rz, p1 = e[2*x+1]*rz;
      *(float2*)(R + x*128 + lane*2) = float2{p0, p1};
      Pr32[x*64 + lane] = cvt_pk_bf16(p0, p1);
      const int j0 = x*128 + lane*2;
      if (j0     >= i+64) s0 += p0;     // dist bucket t=0
      if (j0     <= i-64) s1 += p0;     // dist bucket t=128
      if (j0 + 1 >= i+64) s0 += p1;
      if (j0 + 1 <= i-64) s1 += p1;
    }
    for (int o=32;o;o>>=1){ s0 += __shfl_xor(s0,o); s1 += __shfl_xor(s1,o); }
    {
      const int t = lane + 1;        // 1..64
      const int j = i + 64 - t;
      const float wv = (j>=0 && j<1024) ? R[j] : 0.f;
      Pr[1024 + t] = f2bf(wv);
      if (lane < 63){
        const int t2 = lane + 65;    // 65..127
        const int j2 = i + 64 - t2;
        const float wv2 = (j2>=0 && j2<1024) ? R[j2] : 0.f;
        Pr[1024 + t2] = f2bf(wv2);
      }
      if (lane == 0){ Pr[1024] = f2bf(s0); Pr[1152] = f2bf(s1); }
      if (lane >= 33) Pr[1120 + lane] = 0;  // zero cols 1153..1183
    }
  }
}

// ---------------------------------------------------------------------------
// Elementwise prep kernels
// ---------------------------------------------------------------------------
__global__ __launch_bounds__(256) void planeize(const float* __restrict__ src, u16* __restrict__ dst,
                                                int total, int modeB){
  int idx = blockIdx.x*256 + threadIdx.x;
  if (idx >= total) return;
  int c = idx & 1023, r = idx >> 10;
  float v = src[idx];
  u16 hi = f2bf(v); u16 lo = f2bf(v - bf2f(hi));
  u16* d = dst + (long long)r*3072 + c;
  if (modeB){ d[0]=hi; d[1024]=hi; d[2048]=lo; }
  else      { d[0]=hi; d[1024]=lo; d[2048]=hi; }
}

// qkv -> qF (A planes hi|lo|hi) and kxF rows 0..1023 (B planes hi|hi|lo, k*0.125),
// both in MFMA-fragment-swizzled layout.
__global__ __launch_bounds__(256) void build_qk(const float* __restrict__ qkv,
                                                u16* __restrict__ qF, u16* __restrict__ kxF){
  int idx = blockIdx.x*256 + threadIdx.x;   // ((b*16+h)*1024+n)*64+d
  int d = idx & 63, n = (idx>>6) & 1023, bh = idx >> 16;
  int b = bh >> 4, h = bh & 15;
  long long src = (long long)(b*1024 + n)*3072 + h*64 + d;
  float qv = qkv[src];
  float kv = qkv[src + 1024] * 0.125f;
  u16 qhi=f2bf(qv), qlo=f2bf(qv - bf2f(qhi));
  u16 khi=f2bf(kv), klo=f2bf(kv - bf2f(khi));
  const int lane = (n&15) + (((d&31)>>3)<<4);
  const int elem = d&7, kc0 = d>>5;
  u16* q = qF + ((((long long)bh*64 + (n>>4))*6*64) + lane)*8 + elem;
  q[(kc0+0)*512] = qhi; q[(kc0+2)*512] = qlo; q[(kc0+4)*512] = qhi;
  u16* kx = kxF + ((((long long)bh*80 + (n>>4))*6*64) + lane)*8 + elem;
  kx[(kc0+0)*512] = khi; kx[(kc0+2)*512] = khi; kx[(kc0+4)*512] = klo;
}

// kxF rows 1024..1279: rel_k_emb planes (B-mode), zero pad rows; swizzled.
__global__ __launch_bounds__(256) void build_kxrel(const float* __restrict__ relk, u16* __restrict__ kxF){
  int idx = blockIdx.x*256 + threadIdx.x;   // (bh, t:256, d:64)
  int d = idx & 63, t = (idx>>6) & 255, bh = idx >> 14;
  u16 hi=0, lo=0;
  if (t < 129){ float v = relk[t*64 + d]; hi = f2bf(v); lo = f2bf(v - bf2f(hi)); }
  const int nrow = 1024 + t;
  const int lane = (t&15) + (((d&31)>>3)<<4);
  const int elem = d&7, kc0 = d>>5;
  u16* kx = kxF + ((((long long)bh*80 + (nrow>>4))*6*64) + lane)*8 + elem;
  kx[(kc0+0)*512] = hi; kx[(kc0+2)*512] = hi; kx[(kc0+4)*512] = lo;
}

__global__ __launch_bounds__(256) void build_vT(const float* __restrict__ qkv, u16* __restrict__ vA){
  __shared__ float tb[64][65];
  int bh = blockIdx.x >> 4, ntile = blockIdx.x & 15;
  int b = bh >> 4, h = bh & 15;
  int tid = threadIdx.x;
  int nl = tid >> 2, dc = (tid & 3)*16;
  const float* sp = qkv + (long long)(b*1024 + ntile*64 + nl)*3072 + 2048 + h*64 + dc;
#pragma unroll
  for (int j=0;j<16;j+=4){
    float4 f = *(const float4*)(sp + j);
    tb[dc+j+0][nl]=f.x; tb[dc+j+1][nl]=f.y; tb[dc+j+2][nl]=f.z; tb[dc+j+3][nl]=f.w;
  }
  __syncthreads();
  int d = tid >> 2, nc = (tid & 3)*16;
  u16* dp = vA + ((long long)bh*64 + d)*1184 + ntile*64 + nc;
#pragma unroll
  for (int j=0;j<16;j+=8){
    u16 a0=f2bf(tb[d][nc+j+0]), a1=f2bf(tb[d][nc+j+1]), a2=f2bf(tb[d][nc+j+2]), a3=f2bf(tb[d][nc+j+3]);
    u16 a4=f2bf(tb[d][nc+j+4]), a5=f2bf(tb[d][nc+j+5]), a6=f2bf(tb[d][nc+j+6]), a7=f2bf(tb[d][nc+j+7]);
    uint4 uu; uu.x=a0|((u32)a1<<16); uu.y=a2|((u32)a3<<16); uu.z=a4|((u32)a5<<16); uu.w=a6|((u32)a7<<16);
    *(uint4*)(dp + j) = uu;
  }
}

__global__ __launch_bounds__(256) void build_vText(const float* __restrict__ relv, u16* __restrict__ vA){
  int idx = blockIdx.x*256 + threadIdx.x;   // (bh, d, t:160)
  int t = idx % 160; int rest = idx / 160; int d = rest & 63; int bh = rest >> 6;
  u16 hv = 0;
  if (t < 129) hv = f2bf(relv[t*64 + d]);
  vA[((long long)bh*64 + d)*1184 + 1024 + t] = hv;
}

__global__ __launch_bounds__(256) void build_resS(const float* __restrict__ res, u16* __restrict__ resS){
  int idx = blockIdx.x*256 + threadIdx.x;
  int d = idx & 63, n = (idx>>6) & 1023, bh = idx >> 16;
  int b = bh >> 4, h = bh & 15;
  float v = res[idx];
  u16 hi = f2bf(v), lo = f2bf(v - bf2f(hi));
  u16* p = resS + (long long)(b*1024 + n)*3072 + h*64 + d;
  p[0]=hi; p[1024]=lo; p[2048]=hi;
}

// ---------------------------------------------------------------------------
extern "C" void kernel_launch(void* const* d_in, const int* in_sizes, int n_in,
                              void* d_out, int out_size, void* d_ws, size_t ws_size,
                              hipStream_t stream) {
  const float* x    = (const float*)d_in[0];
  const float* Wqkv = (const float*)d_in[1];
  const float* bqkv = (const float*)d_in[2];
  const float* Wout = (const float*)d_in[3];
  const float* bout = (const float*)d_in[4];
  const float* relk = (const float*)d_in[5];
  const float* relv = (const float*)d_in[6];
  const float* araw = (const float*)d_in[7];
  float* out = (float*)d_out;

  char* w = (char*)d_ws;
  size_t off = 0;
  auto take = [&](size_t bytes)->char*{ char* p = w + off; off += (bytes + 255) & ~(size_t)255; return p; };

  // regionA (90 MB): phase1 {xS|wqS|qkv32} -> per-half P (77.6 MB) -> {resS|woS}
  char* regionA = take(94371840);
  u16*   xS    = (u16*)  (regionA);
  u16*   wqS   = (u16*)  (regionA + 25165824);
  float* qkv32 = (float*)(regionA + 44040192);
  u16*   Ph    = (u16*)  (regionA);         // [32][1024][1184] u16 per half
  u16*   resS  = (u16*)  (regionA);
  u16*   woS   = (u16*)  (regionA + 25165824);
  u16*   qF    = (u16*)take(25165824);      // [64][64][6][64][8]
  u16*   kxF   = (u16*)take(31457280);      // [64][80][6][64][8]
  u16*   vA    = (u16*)take(9699328);       // [64][64][1184]
  u16*   vB    = (u16*)take(9699328);
  float* res   = (float*)take(16777216);    // [64][1024][64]
  (void)ws_size; (void)in_sizes; (void)n_in; (void)out_size;
  // total ~187 MiB

  // phase 1: QKV projection. qk at split-fp32 (K=3072 planes); v hi*hi (K=1024).
  planeize<<<16384,256,0,stream>>>(x,    xS,  4194304, 0);
  planeize<<<12288,256,0,stream>>>(Wqkv, wqS, 3145728, 1);
  gemm8<128,128><<<dim3(16,32,1),512,0,stream>>>(xS, wqS, qkv32, bqkv,
      3072, 3072, 3072, 3072, 2048);
  gemm8<128,128><<<dim3(8,32,1),512,0,stream>>>(xS, wqS + (long long)2048*3072,
      qkv32 + 2048, bqkv + 2048, 1024, 3072, 3072, 3072, 1024);
  build_qk   <<<16384,256,0,stream>>>(qkv32, qF, kxF);
  build_kxrel<<<4096, 256,0,stream>>>(relk, kxF);
  build_vT   <<<1024, 256,0,stream>>>(qkv32, vA);
  build_vText<<<2560, 256,0,stream>>>(relv, vA);

  // phases 2+3 per 32-head half: fused scores/topk/softmax -> P, then 3x AV
  for (int half = 0; half < 2; ++half) {
    const long long zo = (long long)half * 32;
    score_topk<<<2048,1024,0,stream>>>(qF + zo*196608, kxF + zo*245760, Ph);
    av8<<<512,512,0,stream>>>(Ph, vA + zo*75776, vB + zo*75776, res + zo*65536,
        araw, 1184, 0, 0, 1);
    av8<<<512,512,0,stream>>>(Ph, vB + zo*75776, vA + zo*75776, res + zo*65536,
        araw, 1024, 1, 1, 1);
    av8<<<512,512,0,stream>>>(Ph, vA + zo*75776, vB + zo*75776, res + zo*65536,
        araw, 1024, 2, 1, 0);
  }

  // output projection (fp32 via split planes), 8-wave
  build_resS<<<16384,256,0,stream>>>(res, resS);
  planeize  <<<4096, 256,0,stream>>>(Wout, woS, 1048576, 1);
  gemm8<64,128><<<dim3(8,64,1),512,0,stream>>>(resS, woS, out, bout,
      3072, 3072, 3072, 1024, 1024);
}

// Round 9
// 538.105 us; speedup vs baseline: 1.3880x; 1.0341x over previous
//
#include <hip/hip_runtime.h>

typedef unsigned short u16;
typedef unsigned int   u32;
typedef unsigned long long u64;
typedef __bf16 bf16x8 __attribute__((ext_vector_type(8)));
typedef float  floatx4 __attribute__((ext_vector_type(4)));

#define DEV static __device__ __forceinline__

DEV u16 f2bf(float f){ u32 x = __float_as_uint(f); return (u16)((x + 0x7fffu + ((x>>16)&1u)) >> 16); }
DEV float bf2f(u16 h){ return __uint_as_float(((u32)h)<<16); }
// pack two f32 -> two bf16 (RNE), one instruction. dst.lo=cvt(a), dst.hi=cvt(b)
DEV u32 cvt_pk_bf16(float a, float b){ u32 r; asm("v_cvt_pk_bf16_f32 %0, %1, %2" : "=v"(r) : "v"(a), "v"(b)); return r; }

DEV void load_lds16(const u16* g, u16* l){
  __builtin_amdgcn_global_load_lds((const __attribute__((address_space(1))) u32*)g,
                                   (__attribute__((address_space(3))) u32*)l, 16, 0, 0);
}

// Memory-fenced workgroup barrier for raw-pipeline use (rule #18: the bare
// s_barrier builtin is NOT a compiler memory fence — LDS reads / global_load_lds
// can be hoisted across it, which raced in round 7). The empty-asm clobbers pin
// all memory ops on their side of the barrier at IR level; sched_barrier(0)
// pins the machine scheduler. Validated in av8 (round 8, passed).
DEV void barrier_fenced(){
  asm volatile("" ::: "memory");
  __builtin_amdgcn_sched_barrier(0);
  __builtin_amdgcn_s_barrier();
  __builtin_amdgcn_sched_barrier(0);
  asm volatile("" ::: "memory");
}

// ---------------------------------------------------------------------------
// LDS swizzle for [rows][32 u16] tiles (verified bijective, rounds 2-8).
// Read: byte ^= (row&7)<<4. Staging: LDS dest linear, global source byte =
// unswz64(linear dest byte) (row-count agnostic: bits 9+ pass through).
// ---------------------------------------------------------------------------
DEV u32 unswz64(u32 p){
  u32 r0 = ((p>>6) ^ (p>>8)) & 1u;
  u32 b4 = ((p>>4) & 1u) ^ r0;
  u32 b5 = ((p>>5) ^ (p>>7)) & 1u;
  return (p & ~0x70u) | (b4<<4) | (b5<<5) | (r0<<6);
}
DEV bf16x8 ldfrag(const u16* base, int row, int lane){
  u32 off = ((u32)row<<6) + (((u32)lane>>4)<<4);
  off ^= (u32)(row&7)<<4;
  return *(const bf16x8*)((const char*)base + off);
}

// ---------------------------------------------------------------------------
// gemm8 v2: 512-thread 8-wave MODE-0 GEMM with the counted-vmcnt ring
// (T3+T4) validated in av8 (round 8). Round-4/5 post-mortem: the 2-phase
// __syncthreads drain left QKV1 at 23% MfmaUtil / ~3x both rooflines.
// Ring: 4 buffers x (A BM*32 | B BN*32) u16; per step
// { s_waitcnt vmcnt(N); barrier_fenced; ds_read+MFMA; barrier_fenced;
//   stage(s+4) into the just-freed buffer }. N = (inflight steps-1) x
// loads/wave/stage: BM=128 -> every wave 2 loads -> 6/4/2/0 tail;
// BM=64 -> waves 0-3 two loads (A+B: 6/4/2/0), waves 4-7 one (B: 3/2/1/0),
// selected by a wave-uniform branch. Ring invariants identical to av8:
// reads of step s complete before barrier-2 (MFMA's lgkmcnt), restage only
// after barrier-2, reader waits own vmcnt then barrier publishes all waves.
// K ascending, one mfma per k-step per output -> bit-identical C.
// LDS: BM=128: 64 KB (2 blocks/CU at grid 512); BM=64: 48 KB.
// ---------------------------------------------------------------------------
template<int BM, int BN>
__global__ __launch_bounds__(512, 4) void gemm8(
    const u16* __restrict__ A, const u16* __restrict__ Bm, float* __restrict__ C,
    const float* __restrict__ bias, int K, int lda, int ldb, int ldc, int ncmax)
{
  constexpr int MT = (BM/2)/16;           // 4 (BM=128) or 2 (BM=64)
  constexpr int NT = (BN/4)/16;           // 2 (BN=128)
  constexpr int AU = BM*32;               // u16s per A tile
  constexpr int BU = BN*32;               // u16s per B tile
  constexpr int STRIDE = AU + BU;         // u16s per ring buffer
  __shared__ u16 smem[4*STRIDE];          // 64 KB (BM=128) / 48 KB (BM=64)

  const int tid = threadIdx.x, wid = tid>>6, lane = tid&63;
  const int m0 = blockIdx.y * BM, n0 = blockIdx.x * BN;

  const u32 g = unswz64((u32)tid*16);
  const int srow = g>>6, schunk = (g&63)>>1;
  const u16* ga0 = A  + (long long)(m0 + srow)*lda + schunk;  // used iff wid < BM/16
  const u16* gb0 = Bm + (long long)(n0 + srow)*ldb + schunk;

  u16* lA0 = smem + (wid<<9);             // wave-uniform A dest (buffer 0)
  u16* lB0 = smem + AU + (wid<<9);        // wave-uniform B dest (buffer 0)

  const int wm = wid>>2, wn = wid&3;
  const int lr = lane&15, lq = lane>>4;

  auto stage = [&](int s){
    const int c = s & 3;
    if (BM == 128 || wid < 4) load_lds16(ga0 + (s<<5), lA0 + c*STRIDE);
    load_lds16(gb0 + (s<<5), lB0 + c*STRIDE);
  };

  floatx4 acc[MT][NT] = {};
  const int nk = K >> 5;                  // 96 or 32 (always > 4)

#define G_STEP(CC, VA, VB) do { \
    if (BM == 128 || wid < 4) asm volatile("s_waitcnt vmcnt(" VA ")" ::: "memory"); \
    else                      asm volatile("s_waitcnt vmcnt(" VB ")" ::: "memory"); \
    barrier_fenced(); \
    const u16* Asc = smem + (u32)(CC)*STRIDE; \
    const u16* Bsc = Asc + AU; \
    bf16x8 af[MT]; \
    _Pragma("unroll") \
    for (int mt=0; mt<MT; ++mt) af[mt] = ldfrag(Asc, wm*(BM/2) + mt*16 + lr, lane); \
    _Pragma("unroll") \
    for (int nt=0; nt<NT; ++nt) { \
      bf16x8 bfr = ldfrag(Bsc, wn*(BN/4) + nt*16 + lr, lane); \
      _Pragma("unroll") \
      for (int mt=0; mt<MT; ++mt) \
        acc[mt][nt] = __builtin_amdgcn_mfma_f32_16x16x32_bf16(af[mt], bfr, acc[mt][nt], 0, 0, 0); \
    } \
    barrier_fenced(); \
  } while(0)

#pragma unroll
  for (int p = 0; p < 4; ++p) stage(p);

  for (int s = 0; s < nk - 4; ++s){
    G_STEP(s & 3, "6", "3");
    stage(s + 4);                  // into buf (s+4)&3 == s&3, freed by barrier-2
  }
  G_STEP((nk-4) & 3, "6", "3");
  G_STEP((nk-3) & 3, "4", "2");
  G_STEP((nk-2) & 3, "2", "1");
  G_STEP((nk-1) & 3, "0", "0");
#undef G_STEP

#pragma unroll
  for (int nt=0; nt<NT; ++nt) {
    const int col = n0 + wn*(BN/4) + nt*16 + lr;
    if (col < ncmax) {
      const float bv = bias ? bias[col] : 0.f;
#pragma unroll
      for (int mt=0; mt<MT; ++mt) {
#pragma unroll
        for (int r=0; r<4; ++r) {
          const int row = m0 + wm*(BM/2) + mt*16 + lq*4 + r;
          C[(long long)row*ldc + col] = acc[mt][nt][r] + bv;
        }
      }
    }
  }
}

// ---------------------------------------------------------------------------
// av8 v2.1: counted-vmcnt ring pipeline (validated round 8: passed, -33 us).
// 8-buffer LDS ring (64 KB); per step { s_waitcnt vmcnt(7); BARRIER;
// 3 ds_read + 2 MFMA; BARRIER; stage(s+8) }. No vmcnt(0) drain in loop.
// ---------------------------------------------------------------------------
__global__ __launch_bounds__(512, 4) void av8(
    const u16* __restrict__ P,    // [z][1024][1184]
    const u16* __restrict__ V,    // [z][64][1184]
    u16* __restrict__ vout,       // [z][64][1184]
    float* __restrict__ resb,     // [z][1024][64]
    const float* __restrict__ araw, int K, int order, int accum, int wv)
{
  __shared__ u16 smem[32768];     // 8 ring buffers x (As 2048 | Bs 2048) u16 = 64 KB
                                  // epilogue reuses [0..8704) as 64x136 transpose
  const int tid = threadIdx.x, wid = tid>>6, lane = tid&63;
  const int L = blockIdx.x;
  const int z  = (L & 7) + ((L >> 7) << 3);   // 4 z per XCD, 16 m-blocks clustered
  const int m0 = ((L >> 3) & 15) * 64;
  const int lr = lane&15, lq = lane>>4;

  const int sw = wid & 3;
  const u32 g = unswz64((u32)(sw*1024 + lane*16));
  const int srow = g>>6, schunk = (g&63)>>1;
  const u16* gsrc = (wid < 4)
      ? P + (long long)z*1212416 + (long long)(m0 + srow)*1184 + schunk
      : V + (long long)z*75776   + (long long)srow*1184 + schunk;
  const int bsel = (wid < 4) ? 0 : 2048;      // A half / B half of each ring buffer
  u16* ldst0 = smem + bsel + (sw<<9);         // wave-uniform LDS dest (+ c*4096)

  const int wm = wid>>2, wn = wid&3;
  const int wm32 = wm*32, wn16 = wn*16;
  const int nk = K >> 5;                      // 37 or 32 (always > 8)

  auto stage = [&](int p){ load_lds16(gsrc + (p<<5), ldst0 + ((p&7)<<12)); };

  floatx4 acc[2] = {};

#define AV_STEP(CC, VC) do { \
    asm volatile("s_waitcnt vmcnt(" VC ")" ::: "memory"); \
    barrier_fenced(); \
    const u16* Asc = smem + ((u32)(CC)<<12); \
    const u16* Bsc = Asc + 2048; \
    bf16x8 bfr = ldfrag(Bsc, wn16 + lr, lane); \
    bf16x8 af0 = ldfrag(Asc, wm32 + lr, lane); \
    bf16x8 af1 = ldfrag(Asc, wm32 + 16 + lr, lane); \
    acc[0] = __builtin_amdgcn_mfma_f32_16x16x32_bf16(af0, bfr, acc[0], 0, 0, 0); \
    acc[1] = __builtin_amdgcn_mfma_f32_16x16x32_bf16(af1, bfr, acc[1], 0, 0, 0); \
    barrier_fenced(); \
  } while(0)

#pragma unroll
  for (int p = 0; p < 8; ++p) stage(p);

  for (int s = 0; s < nk - 8; ++s){
    AV_STEP(s & 7, "7");
    stage(s + 8);                  // into buf (s+8)&7 == s&7, just freed by barrier-2
  }
  AV_STEP((nk-8) & 7, "7");
  AV_STEP((nk-7) & 7, "6");
  AV_STEP((nk-6) & 7, "5");
  AV_STEP((nk-5) & 7, "4");
  AV_STEP((nk-4) & 7, "3");
  AV_STEP((nk-3) & 7, "2");
  AV_STEP((nk-2) & 7, "1");
  AV_STEP((nk-1) & 7, "0");
#undef AV_STEP

  const int h = z & 15;
  const float alpha = 1.f/(1.f + __expf(-araw[order*16 + h]));
  float* rb = resb + (long long)z * 65536;    // res[z][1024][64]
  const int d = wn16 + lr;                    // C col -> V/d row
  __syncthreads();                            // ring reads done before smem reuse
#pragma unroll
  for (int mt=0; mt<2; ++mt){
#pragma unroll
    for (int r=0; r<4; ++r){
      const int row = wm32 + mt*16 + lq*4 + r;
      const float v = acc[mt][r];
      const long long ri = (long long)(m0+row)*64 + d;
      rb[ri] = accum ? (rb[ri] + alpha*v) : (alpha*v);
      smem[d*136 + row] = f2bf(v);
    }
  }
  __syncthreads();
  if (wv){
    const int dd = tid>>3, cc = (tid&7)*8;
    u16* vp = vout + (long long)z*75776 + (long long)dd*1184 + m0 + cc;
    const u16* sp = smem + dd*136 + cc;
    uint4 uu;
    uu.x = sp[0] | ((u32)sp[1]<<16);
    uu.y = sp[2] | ((u32)sp[3]<<16);
    uu.z = sp[4] | ((u32)sp[5]<<16);
    uu.w = sp[6] | ((u32)sp[7]<<16);
    *(uint4*)(vp) = uu;
  }
}

// ---------------------------------------------------------------------------
// Fused scores + top-k + softmax, v4 (unchanged).
// ---------------------------------------------------------------------------
__global__ __launch_bounds__(1024, 8) void score_topk(
    const u16* __restrict__ qF,   // [z][64][6][64][8]
    const u16* __restrict__ kxF,  // [z][80][6][64][8]
    u16* __restrict__ P)          // [z][1024][1184]
{
  constexpr int SROW = 1156;
  __shared__ float sm[16*SROW];   // 73,984 B -> 2 blocks/CU
  const int tid = threadIdx.x, wid = tid>>6, lane = tid&63;
  const int L = blockIdx.x;
  const int z  = (L & 7) + ((L >> 9) << 3);
  const int mt = (L >> 3) & 63;
  const int m0 = mt*16;
  const int lr = lane&15, lq = lane>>4;

  const u16* Aq = qF + (((long long)z*64 + mt)*6*64 + lane)*8;
  const u16* Bq = kxF + ((long long)z*80*6*64 + lane)*8;

  bf16x8 af[6];
#pragma unroll
  for (int kc=0;kc<6;++kc) af[kc] = *(const bf16x8*)(Aq + kc*512);

  const int base = wid*5;
  {
    floatx4 acc[5];
#pragma unroll
    for (int t=0;t<5;++t) acc[t] = floatx4{0.f,0.f,0.f,0.f};
#pragma unroll
    for (int t=0;t<5;++t){
      if (base + t < 73){
        const u16* bp = Bq + (long long)(base+t)*3072;   // 6*512
        bf16x8 b0 = *(const bf16x8*)(bp);
        bf16x8 b1 = *(const bf16x8*)(bp + 512);
        bf16x8 b2 = *(const bf16x8*)(bp + 1024);
        bf16x8 b3 = *(const bf16x8*)(bp + 1536);
        bf16x8 b4 = *(const bf16x8*)(bp + 2048);
        bf16x8 b5 = *(const bf16x8*)(bp + 2560);
        acc[t] = __builtin_amdgcn_mfma_f32_16x16x32_bf16(af[0], b0, acc[t], 0, 0, 0);
        acc[t] = __builtin_amdgcn_mfma_f32_16x16x32_bf16(af[1], b1, acc[t], 0, 0, 0);
        acc[t] = __builtin_amdgcn_mfma_f32_16x16x32_bf16(af[2], b2, acc[t], 0, 0, 0);
        acc[t] = __builtin_amdgcn_mfma_f32_16x16x32_bf16(af[3], b3, acc[t], 0, 0, 0);
        acc[t] = __builtin_amdgcn_mfma_f32_16x16x32_bf16(af[4], b4, acc[t], 0, 0, 0);
        acc[t] = __builtin_amdgcn_mfma_f32_16x16x32_bf16(af[5], b5, acc[t], 0, 0, 0);
      }
    }
#pragma unroll
    for (int t=0;t<5;++t){
      if (base + t < 73){
        const int col = (base+t)*16 + lr;
        if (col < 1153){
#pragma unroll
          for (int r=0;r<4;++r) sm[(lq*4+r)*SROW + col] = acc[t][r];
        }
      }
    }
  }
  __syncthreads();

  {
    const int row = wid;
    const int i = m0 + row;
    float* R = sm + row*SROW;

    float v[16];
#pragma unroll
    for (int x=0;x<8;++x){
      float2 f = *(const float2*)(R + x*128 + lane*2);
      v[2*x] = f.x; v[2*x+1] = f.y;
    }
#pragma unroll
    for (int x=0;x<16;++x){
      const int j = (x>>1)*128 + lane*2 + (x&1);
      int dl = i - j; dl = dl > 64 ? 64 : (dl < -64 ? -64 : dl);
      v[x] += R[1024 + dl + 64];
    }
    u32 u[16];
#pragma unroll
    for (int x=0;x<16;++x){
      u32 bb = __float_as_uint(v[x]);
      u[x] = bb ^ ((u32)((int)bb >> 31) | 0x80000000u);
    }
    u32 thr = 0;
#pragma unroll 1
    for (int bit=31; bit>=0; --bit){
      const u32 cand = thr | (1u<<bit);
      int c = 0;
#pragma unroll
      for (int x=0;x<16;++x) c += __popcll(__ballot(u[x] >= cand));
      if (c == 256){
        u32 mn = 0xFFFFFFFFu;
#pragma unroll
        for (int x=0;x<16;++x) if (u[x] >= cand && u[x] < mn) mn = u[x];
        for (int o=32;o;o>>=1){ u32 t = __shfl_xor(mn, o); mn = t < mn ? t : mn; }
        thr = mn;
        break;
      }
      if (c > 256) thr = cand;
    }
    float m = -3.0e38f;
#pragma unroll
    for (int x=0;x<16;++x) m = fmaxf(m, v[x]);
    for (int o=32;o;o>>=1) m = fmaxf(m, __shfl_xor(m, o));
    float e[16]; float Z = 0.f;
#pragma unroll
    for (int x=0;x<16;++x){
      e[x] = (u[x] >= thr) ? __expf(v[x]-m) : 0.f;
      Z += e[x];
    }
    for (int o=32;o;o>>=1) Z += __shfl_xor(Z, o);
    const float rz = 1.f / Z;

    u16* Pr = P + ((long long)z*1024 + i)*1184;
    u32* Pr32 = (u32*)Pr;
    float s0 = 0.f, s1 = 0.f;
#pragma unroll
    for (int x=0;x<8;++x){
      const float p0 = e[2*x]*rz, p1 = e[2*x+1]*rz;
      *(float2*)(R + x*128 + lane*2) = float2{p0, p1};
      Pr32[x*64 + lane] = cvt_pk_bf16(p0, p1);
      const int j0 = x*128 + lane*2;
      if (j0     >= i+64) s0 += p0;     // dist bucket t=0
      if (j0     <= i-64) s1 += p0;     // dist bucket t=128
      if (j0 + 1 >= i+64) s0 += p1;
      if (j0 + 1 <= i-64) s1 += p1;
    }
    for (int o=32;o;o>>=1){ s0 += __shfl_xor(s0,o); s1 += __shfl_xor(s1,o); }
    {
      const int t = lane + 1;        // 1..64
      const int j = i + 64 - t;
      const float wv = (j>=0 && j<1024) ? R[j] : 0.f;
      Pr[1024 + t] = f2bf(wv);
      if (lane < 63){
        const int t2 = lane + 65;    // 65..127
        const int j2 = i + 64 - t2;
        const float wv2 = (j2>=0 && j2<1024) ? R[j2] : 0.f;
        Pr[1024 + t2] = f2bf(wv2);
      }
      if (lane == 0){ Pr[1024] = f2bf(s0); Pr[1152] = f2bf(s1); }
      if (lane >= 33) Pr[1120 + lane] = 0;  // zero cols 1153..1183
    }
  }
}

// ---------------------------------------------------------------------------
// Elementwise prep kernels
// ---------------------------------------------------------------------------
__global__ __launch_bounds__(256) void planeize(const float* __restrict__ src, u16* __restrict__ dst,
                                                int total, int modeB){
  int idx = blockIdx.x*256 + threadIdx.x;
  if (idx >= total) return;
  int c = idx & 1023, r = idx >> 10;
  float v = src[idx];
  u16 hi = f2bf(v); u16 lo = f2bf(v - bf2f(hi));
  u16* d = dst + (long long)r*3072 + c;
  if (modeB){ d[0]=hi; d[1024]=hi; d[2048]=lo; }
  else      { d[0]=hi; d[1024]=lo; d[2048]=hi; }
}

// qkv -> qF (A planes hi|lo|hi) and kxF rows 0..1023 (B planes hi|hi|lo, k*0.125),
// both in MFMA-fragment-swizzled layout.
__global__ __launch_bounds__(256) void build_qk(const float* __restrict__ qkv,
                                                u16* __restrict__ qF, u16* __restrict__ kxF){
  int idx = blockIdx.x*256 + threadIdx.x;   // ((b*16+h)*1024+n)*64+d
  int d = idx & 63, n = (idx>>6) & 1023, bh = idx >> 16;
  int b = bh >> 4, h = bh & 15;
  long long src = (long long)(b*1024 + n)*3072 + h*64 + d;
  float qv = qkv[src];
  float kv = qkv[src + 1024] * 0.125f;
  u16 qhi=f2bf(qv), qlo=f2bf(qv - bf2f(qhi));
  u16 khi=f2bf(kv), klo=f2bf(kv - bf2f(khi));
  const int lane = (n&15) + (((d&31)>>3)<<4);
  const int elem = d&7, kc0 = d>>5;
  u16* q = qF + ((((long long)bh*64 + (n>>4))*6*64) + lane)*8 + elem;
  q[(kc0+0)*512] = qhi; q[(kc0+2)*512] = qlo; q[(kc0+4)*512] = qhi;
  u16* kx = kxF + ((((long long)bh*80 + (n>>4))*6*64) + lane)*8 + elem;
  kx[(kc0+0)*512] = khi; kx[(kc0+2)*512] = khi; kx[(kc0+4)*512] = klo;
}

// kxF rows 1024..1279: rel_k_emb planes (B-mode), zero pad rows; swizzled.
__global__ __launch_bounds__(256) void build_kxrel(const float* __restrict__ relk, u16* __restrict__ kxF){
  int idx = blockIdx.x*256 + threadIdx.x;   // (bh, t:256, d:64)
  int d = idx & 63, t = (idx>>6) & 255, bh = idx >> 14;
  u16 hi=0, lo=0;
  if (t < 129){ float v = relk[t*64 + d]; hi = f2bf(v); lo = f2bf(v - bf2f(hi)); }
  const int nrow = 1024 + t;
  const int lane = (t&15) + (((d&31)>>3)<<4);
  const int elem = d&7, kc0 = d>>5;
  u16* kx = kxF + ((((long long)bh*80 + (nrow>>4))*6*64) + lane)*8 + elem;
  kx[(kc0+0)*512] = hi; kx[(kc0+2)*512] = hi; kx[(kc0+4)*512] = lo;
}

__global__ __launch_bounds__(256) void build_vT(const float* __restrict__ qkv, u16* __restrict__ vA){
  __shared__ float tb[64][65];
  int bh = blockIdx.x >> 4, ntile = blockIdx.x & 15;
  int b = bh >> 4, h = bh & 15;
  int tid = threadIdx.x;
  int nl = tid >> 2, dc = (tid & 3)*16;
  const float* sp = qkv + (long long)(b*1024 + ntile*64 + nl)*3072 + 2048 + h*64 + dc;
#pragma unroll
  for (int j=0;j<16;j+=4){
    float4 f = *(const float4*)(sp + j);
    tb[dc+j+0][nl]=f.x; tb[dc+j+1][nl]=f.y; tb[dc+j+2][nl]=f.z; tb[dc+j+3][nl]=f.w;
  }
  __syncthreads();
  int d = tid >> 2, nc = (tid & 3)*16;
  u16* dp = vA + ((long long)bh*64 + d)*1184 + ntile*64 + nc;
#pragma unroll
  for (int j=0;j<16;j+=8){
    u16 a0=f2bf(tb[d][nc+j+0]), a1=f2bf(tb[d][nc+j+1]), a2=f2bf(tb[d][nc+j+2]), a3=f2bf(tb[d][nc+j+3]);
    u16 a4=f2bf(tb[d][nc+j+4]), a5=f2bf(tb[d][nc+j+5]), a6=f2bf(tb[d][nc+j+6]), a7=f2bf(tb[d][nc+j+7]);
    uint4 uu; uu.x=a0|((u32)a1<<16); uu.y=a2|((u32)a3<<16); uu.z=a4|((u32)a5<<16); uu.w=a6|((u32)a7<<16);
    *(uint4*)(dp + j) = uu;
  }
}

__global__ __launch_bounds__(256) void build_vText(const float* __restrict__ relv, u16* __restrict__ vA){
  int idx = blockIdx.x*256 + threadIdx.x;   // (bh, d, t:160)
  int t = idx % 160; int rest = idx / 160; int d = rest & 63; int bh = rest >> 6;
  u16 hv = 0;
  if (t < 129) hv = f2bf(relv[t*64 + d]);
  vA[((long long)bh*64 + d)*1184 + 1024 + t] = hv;
}

__global__ __launch_bounds__(256) void build_resS(const float* __restrict__ res, u16* __restrict__ resS){
  int idx = blockIdx.x*256 + threadIdx.x;
  int d = idx & 63, n = (idx>>6) & 1023, bh = idx >> 16;
  int b = bh >> 4, h = bh & 15;
  float v = res[idx];
  u16 hi = f2bf(v), lo = f2bf(v - bf2f(hi));
  u16* p = resS + (long long)(b*1024 + n)*3072 + h*64 + d;
  p[0]=hi; p[1024]=lo; p[2048]=hi;
}

// ---------------------------------------------------------------------------
extern "C" void kernel_launch(void* const* d_in, const int* in_sizes, int n_in,
                              void* d_out, int out_size, void* d_ws, size_t ws_size,
                              hipStream_t stream) {
  const float* x    = (const float*)d_in[0];
  const float* Wqkv = (const float*)d_in[1];
  const float* bqkv = (const float*)d_in[2];
  const float* Wout = (const float*)d_in[3];
  const float* bout = (const float*)d_in[4];
  const float* relk = (const float*)d_in[5];
  const float* relv = (const float*)d_in[6];
  const float* araw = (const float*)d_in[7];
  float* out = (float*)d_out;

  char* w = (char*)d_ws;
  size_t off = 0;
  auto take = [&](size_t bytes)->char*{ char* p = w + off; off += (bytes + 255) & ~(size_t)255; return p; };

  // regionA (90 MB): phase1 {xS|wqS|qkv32} -> per-half P (77.6 MB) -> {resS|woS}
  char* regionA = take(94371840);
  u16*   xS    = (u16*)  (regionA);
  u16*   wqS   = (u16*)  (regionA + 25165824);
  float* qkv32 = (float*)(regionA + 44040192);
  u16*   Ph    = (u16*)  (regionA);         // [32][1024][1184] u16 per half
  u16*   resS  = (u16*)  (regionA);
  u16*   woS   = (u16*)  (regionA + 25165824);
  u16*   qF    = (u16*)take(25165824);      // [64][64][6][64][8]
  u16*   kxF   = (u16*)take(31457280);      // [64][80][6][64][8]
  u16*   vA    = (u16*)take(9699328);       // [64][64][1184]
  u16*   vB    = (u16*)take(9699328);
  float* res   = (float*)take(16777216);    // [64][1024][64]
  (void)ws_size; (void)in_sizes; (void)n_in; (void)out_size;
  // total ~187 MiB

  // phase 1: QKV projection. qk at split-fp32 (K=3072 planes); v hi*hi (K=1024).
  planeize<<<16384,256,0,stream>>>(x,    xS,  4194304, 0);
  planeize<<<12288,256,0,stream>>>(Wqkv, wqS, 3145728, 1);
  gemm8<128,128><<<dim3(16,32,1),512,0,stream>>>(xS, wqS, qkv32, bqkv,
      3072, 3072, 3072, 3072, 2048);
  gemm8<128,128><<<dim3(8,32,1),512,0,stream>>>(xS, wqS + (long long)2048*3072,
      qkv32 + 2048, bqkv + 2048, 1024, 3072, 3072, 3072, 1024);
  build_qk   <<<16384,256,0,stream>>>(qkv32, qF, kxF);
  build_kxrel<<<4096, 256,0,stream>>>(relk, kxF);
  build_vT   <<<1024, 256,0,stream>>>(qkv32, vA);
  build_vText<<<2560, 256,0,stream>>>(relv, vA);

  // phases 2+3 per 32-head half: fused scores/topk/softmax -> P, then 3x AV
  for (int half = 0; half < 2; ++half) {
    const long long zo = (long long)half * 32;
    score_topk<<<2048,1024,0,stream>>>(qF + zo*196608, kxF + zo*245760, Ph);
    av8<<<512,512,0,stream>>>(Ph, vA + zo*75776, vB + zo*75776, res + zo*65536,
        araw, 1184, 0, 0, 1);
    av8<<<512,512,0,stream>>>(Ph, vB + zo*75776, vA + zo*75776, res + zo*65536,
        araw, 1024, 1, 1, 1);
    av8<<<512,512,0,stream>>>(Ph, vA + zo*75776, vB + zo*75776, res + zo*65536,
        araw, 1024, 2, 1, 0);
  }

  // output projection (fp32 via split planes), 8-wave
  build_resS<<<16384,256,0,stream>>>(res, resS);
  planeize  <<<4096, 256,0,stream>>>(Wout, woS, 1048576, 1);
  gemm8<64,128><<<dim3(8,64,1),512,0,stream>>>(resS, woS, out, bout,
      3072, 3072, 3072, 1024, 1024);
}